// Round 1
// baseline (436.303 us; speedup 1.0000x reference)
//
#include <hip/hip_runtime.h>
#include <cstdint>
#include <cstddef>

#define HB 2048          // level-1/2 histogram buckets (11 bits)
#define IOU_T 0.5f
#define VV0 0.1f
#define VV1 0.2f

__device__ __forceinline__ float sl1(float x) {
    float ax = fabsf(x);
    return ax < 1.0f ? 0.5f * x * x : ax - 0.5f;
}

// ---------------- Kernel A: per-truth argmax over prior slices ----------------
__global__ __launch_bounds__(256) void kA_best_prior(
    const float* __restrict__ targets, const float* __restrict__ priors,
    float* __restrict__ bpi_val, int* __restrict__ bpi_idx,
    int N, int NOBJ, int SLICES, int CHUNK)
{
    const int s = blockIdx.x, b = blockIdx.y, t = threadIdx.x;
    __shared__ float tb[16 * 4];
    __shared__ float ta[16];
    __shared__ float rv[16 * 256];
    __shared__ int   ri[16 * 256];

    if (t < 16) {
        if (t < NOBJ) {
            const float* tr = targets + ((size_t)b * NOBJ + t) * 5;
            float x0 = tr[0], y0 = tr[1], x1 = tr[2], y1 = tr[3];
            tb[t * 4 + 0] = x0; tb[t * 4 + 1] = y0;
            tb[t * 4 + 2] = x1; tb[t * 4 + 3] = y1;
            ta[t] = (x1 - x0) * (y1 - y0);
        } else {
            tb[t * 4 + 0] = 0.f; tb[t * 4 + 1] = 0.f;
            tb[t * 4 + 2] = 0.f; tb[t * 4 + 3] = 0.f;
            ta[t] = 0.f;
        }
    }
    __syncthreads();

    float bv[16]; int bi[16];
#pragma unroll
    for (int j = 0; j < 16; j++) { bv[j] = -1.0f; bi[j] = 0x7fffffff; }

    const int start = s * CHUNK;
    const int end = min(start + CHUNK, N);
    for (int i = start + t; i < end; i += 256) {
        float4 p = ((const float4*)priors)[i];
        float bx0 = p.x - p.z * 0.5f, by0 = p.y - p.w * 0.5f;
        float bx1 = p.x + p.z * 0.5f, by1 = p.y + p.w * 0.5f;
        float ab = (bx1 - bx0) * (by1 - by0);
#pragma unroll
        for (int j = 0; j < 16; j++) {
            float iw = fminf(tb[j * 4 + 2], bx1) - fmaxf(tb[j * 4 + 0], bx0);
            float ih = fminf(tb[j * 4 + 3], by1) - fmaxf(tb[j * 4 + 1], by0);
            iw = fmaxf(iw, 0.f); ih = fmaxf(ih, 0.f);
            float inter = iw * ih;
            float iou = inter / (ta[j] + ab - inter);
            if (iou > bv[j] || (iou == bv[j] && i < bi[j])) { bv[j] = iou; bi[j] = i; }
        }
    }
#pragma unroll
    for (int j = 0; j < 16; j++) { rv[j * 256 + t] = bv[j]; ri[j * 256 + t] = bi[j]; }
    __syncthreads();
    for (int st = 128; st >= 1; st >>= 1) {
        if (t < st) {
#pragma unroll
            for (int j = 0; j < 16; j++) {
                float v2 = rv[j * 256 + t + st]; int i2 = ri[j * 256 + t + st];
                float v1 = rv[j * 256 + t];      int i1 = ri[j * 256 + t];
                if (v2 > v1 || (v2 == v1 && i2 < i1)) { rv[j * 256 + t] = v2; ri[j * 256 + t] = i2; }
            }
        }
        __syncthreads();
    }
    if (t < NOBJ) {
        int o = (b * SLICES + s) * 16 + t;
        bpi_val[o] = rv[t * 256];
        bpi_idx[o] = ri[t * 256];
    }
}

// ---------------- Kernel B: match + loss_l + lc + histogram ----------------
__global__ __launch_bounds__(256) void kB_main(
    const float* __restrict__ loc, const float* __restrict__ conf,
    const float* __restrict__ targets, const float* __restrict__ priors,
    const float* __restrict__ bpi_val, const int* __restrict__ bpi_idx,
    float* __restrict__ lc_out, unsigned* __restrict__ g_histc, float* __restrict__ g_hists,
    int* __restrict__ num_pos, float* __restrict__ acc,
    int N, int NOBJ, int C, int SLICES)
{
    const int b = blockIdx.y;
    const int t = threadIdx.x;
    const int i = blockIdx.x * 256 + t;

    __shared__ float tb[16 * 4];
    __shared__ float ta[16];
    __shared__ float tl[16];
    __shared__ int   bpi_s[16];
    __shared__ unsigned hc[HB];
    __shared__ float hs[HB];
    __shared__ float redA[256], redB[256], redC[256];

    for (int q = t; q < HB; q += 256) { hc[q] = 0u; hs[q] = 0.f; }
    if (t < 16) {
        if (t < NOBJ) {
            const float* tr = targets + ((size_t)b * NOBJ + t) * 5;
            float x0 = tr[0], y0 = tr[1], x1 = tr[2], y1 = tr[3];
            tb[t * 4 + 0] = x0; tb[t * 4 + 1] = y0;
            tb[t * 4 + 2] = x1; tb[t * 4 + 3] = y1;
            ta[t] = (x1 - x0) * (y1 - y0);
            tl[t] = tr[4];
            float bv = -1.f; int bi = 0x7fffffff;
            for (int s2 = 0; s2 < SLICES; s2++) {
                int o = (b * SLICES + s2) * 16 + t;
                float v = bpi_val[o]; int idx = bpi_idx[o];
                if (v > bv || (v == bv && idx < bi)) { bv = v; bi = idx; }
            }
            bpi_s[t] = bi;
        } else {
            tb[t * 4 + 0] = 0.f; tb[t * 4 + 1] = 0.f; tb[t * 4 + 2] = 0.f; tb[t * 4 + 3] = 0.f;
            ta[t] = 0.f; tl[t] = 0.f; bpi_s[t] = -1;
        }
    }
    __syncthreads();

    float ll = 0.f, plc = 0.f, np = 0.f;
    if (i < N) {
        float4 p = ((const float4*)priors)[i];
        float bx0 = p.x - p.z * 0.5f, by0 = p.y - p.w * 0.5f;
        float bx1 = p.x + p.z * 0.5f, by1 = p.y + p.w * 0.5f;
        float ab = (bx1 - bx0) * (by1 - by0);
        float bto = -1.f; int bti = 0;
        for (int j = 0; j < NOBJ; j++) {
            float iw = fminf(tb[j * 4 + 2], bx1) - fmaxf(tb[j * 4 + 0], bx0);
            float ih = fminf(tb[j * 4 + 3], by1) - fmaxf(tb[j * 4 + 1], by0);
            iw = fmaxf(iw, 0.f); ih = fmaxf(ih, 0.f);
            float inter = iw * ih;
            float iou = inter / (ta[j] + ab - inter);
            if (iou > bto) { bto = iou; bti = j; }   // first-argmax over truths
        }
        for (int j = 0; j < NOBJ; j++)
            if (bpi_s[j] == i) { bto = 2.0f; bti = j; }  // override, last j wins
        bool pos = !(bto < IOU_T);
        if (pos) {
            float mx0 = tb[bti * 4 + 0], my0 = tb[bti * 4 + 1];
            float mx1 = tb[bti * 4 + 2], my1 = tb[bti * 4 + 3];
            float gcx = ((mx0 + mx1) * 0.5f - p.x) / (VV0 * p.z);
            float gcy = ((my0 + my1) * 0.5f - p.y) / (VV0 * p.w);
            float gw = logf((mx1 - mx0) / p.z) / VV1;
            float gh = logf((my1 - my0) / p.w) / VV1;
            float4 ld = ((const float4*)loc)[(size_t)b * N + i];
            ll = sl1(ld.x - gcx) + sl1(ld.y - gcy) + sl1(ld.z - gw) + sl1(ld.w - gh);
            np = 1.f;
        }
        int cf = pos ? ((int)tl[bti] + 1) : 0;
        const float* cr = conf + ((size_t)b * N + i) * C;
        float m = cr[0];
        for (int c = 1; c < C; c++) m = fmaxf(m, cr[c]);
        float ssum = 0.f;
        for (int c = 0; c < C; c++) ssum += expf(cr[c] - m);
        float lse = m + logf(ssum);
        float lossc = lse - cr[cf];
        if (pos) plc = lossc;
        float lcv = pos ? 0.f : lossc;
        lcv = fmaxf(lcv, 0.f);
        lc_out[(size_t)b * N + i] = lcv;
        unsigned u = __float_as_uint(lcv);
        atomicAdd(&hc[u >> 20], 1u);
        atomicAdd(&hs[u >> 20], lcv);
    }

    redA[t] = ll; redB[t] = plc; redC[t] = np;
    __syncthreads();
    for (int st = 128; st >= 1; st >>= 1) {
        if (t < st) { redA[t] += redA[t + st]; redB[t] += redB[t + st]; redC[t] += redC[t + st]; }
        __syncthreads();
    }
    if (t == 0) {
        atomicAdd(&acc[0], redA[0]);
        atomicAdd(&acc[1], redB[0]);
        atomicAdd(&num_pos[b], (int)redC[0]);
    }
    __syncthreads();
    for (int q = t; q < HB; q += 256) {
        unsigned c = hc[q];
        if (c) {
            atomicAdd(&g_histc[(size_t)b * HB + q], c);
            atomicAdd(&g_hists[(size_t)b * HB + q], hs[q]);
        }
    }
}

// ---------------- Kernel C: 3-level radix select top-k sum ----------------
__device__ __forceinline__ void suffix_scan(int* cnt, float* sm, int n, int t) {
    for (int d = 1; d < n; d <<= 1) {
        int tc[8]; float ts[8];
        int r = 0;
        for (int q = t; q < n; q += 256, r++) {
            int src = q + d;
            tc[r] = (src < n) ? cnt[src] : 0;
            ts[r] = (src < n) ? sm[src] : 0.f;
        }
        __syncthreads();
        r = 0;
        for (int q = t; q < n; q += 256, r++) { cnt[q] += tc[r]; sm[q] += ts[r]; }
        __syncthreads();
    }
}

__global__ __launch_bounds__(256) void kC_topk(
    const float* __restrict__ lc, const unsigned* __restrict__ g_histc,
    const float* __restrict__ g_hists, const int* __restrict__ num_pos,
    float* __restrict__ acc, int N)
{
    const int b = blockIdx.x, t = threadIdx.x;
    __shared__ int cnt[HB];
    __shared__ float sm[HB];
    __shared__ int s_strad, s_krem;
    __shared__ float s_above;

    int k = min(3 * num_pos[b], N - 1);
    if (k <= 0) return;   // uniform per block

    // ---- Level 1: bits [30:20] ----
    for (int q = t; q < HB; q += 256) { cnt[q] = (int)g_histc[(size_t)b * HB + q]; sm[q] = g_hists[(size_t)b * HB + q]; }
    __syncthreads();
    suffix_scan(cnt, sm, HB, t);
    for (int q = t; q < HB; q += 256) {
        int incl = cnt[q];
        int excl = (q < HB - 1) ? cnt[q + 1] : 0;
        if (excl < k && k <= incl) {
            s_strad = q; s_krem = k - excl;
            s_above = (q < HB - 1) ? sm[q + 1] : 0.f;
        }
    }
    __syncthreads();
    int s1 = s_strad, k2 = s_krem;
    float total = s_above;
    __syncthreads();

    // ---- Level 2: bits [19:9] within bucket s1 ----
    for (int q = t; q < HB; q += 256) { cnt[q] = 0; sm[q] = 0.f; }
    __syncthreads();
    const float* lcb = lc + (size_t)b * N;
    for (int i = t; i < N; i += 256) {
        float v = lcb[i];
        unsigned u = __float_as_uint(v);
        if ((int)(u >> 20) == s1) {
            int q = (int)((u >> 9) & 0x7FF);
            atomicAdd(&cnt[q], 1); atomicAdd(&sm[q], v);
        }
    }
    __syncthreads();
    suffix_scan(cnt, sm, HB, t);
    for (int q = t; q < HB; q += 256) {
        int incl = cnt[q];
        int excl = (q < HB - 1) ? cnt[q + 1] : 0;
        if (excl < k2 && k2 <= incl) {
            s_strad = q; s_krem = k2 - excl;
            s_above = (q < HB - 1) ? sm[q + 1] : 0.f;
        }
    }
    __syncthreads();
    int s2 = s_strad, k3 = s_krem;
    total += s_above;
    __syncthreads();

    // ---- Level 3: bits [8:0] within (s1,s2) ----
    for (int q = t; q < 512; q += 256) { cnt[q] = 0; sm[q] = 0.f; }
    __syncthreads();
    unsigned pref = (((unsigned)s1) << 11) | (unsigned)s2;
    for (int i = t; i < N; i += 256) {
        float v = lcb[i];
        unsigned u = __float_as_uint(v);
        if ((u >> 9) == pref) {
            int q = (int)(u & 0x1FF);
            atomicAdd(&cnt[q], 1); atomicAdd(&sm[q], v);
        }
    }
    __syncthreads();
    suffix_scan(cnt, sm, 512, t);
    for (int q = t; q < 512; q += 256) {
        int incl = cnt[q];
        int excl = (q < 511) ? cnt[q + 1] : 0;
        if (excl < k3 && k3 <= incl) {
            s_strad = q; s_krem = k3 - excl;
            s_above = (q < 511) ? sm[q + 1] : 0.f;
        }
    }
    __syncthreads();
    int s3 = s_strad, krem = s_krem;
    total += s_above;
    float tval = __uint_as_float((((unsigned)s1) << 20) | (((unsigned)s2) << 9) | (unsigned)s3);
    total += (float)krem * tval;
    if (t == 0) atomicAdd(&acc[1], total);
}

// ---------------- Kernel D: finalize ----------------
__global__ void kD_final(const int* __restrict__ num_pos, const float* __restrict__ acc,
                         float* __restrict__ out, int B)
{
    if (threadIdx.x == 0 && blockIdx.x == 0) {
        int nt = 0;
        for (int b = 0; b < B; b++) nt += num_pos[b];
        float n = (float)nt;
        out[0] = acc[0] / n;
        out[1] = acc[1] / n;
    }
}

extern "C" void kernel_launch(void* const* d_in, const int* in_sizes, int n_in,
                              void* d_out, int out_size, void* d_ws, size_t ws_size,
                              hipStream_t stream)
{
    const float* loc     = (const float*)d_in[0];
    const float* conf    = (const float*)d_in[1];
    const float* targets = (const float*)d_in[2];
    const float* priors  = (const float*)d_in[3];
    float* out = (float*)d_out;

    const int N = in_sizes[3] / 4;
    const int BN = in_sizes[0] / 4;
    const int B = BN / N;
    const int C = in_sizes[1] / BN;
    const int NOBJ = in_sizes[2] / (B * 5);
    const int SLICES = 8;
    const int CHUNK = (N + SLICES - 1) / SLICES;

    // workspace layout
    char* w = (char*)d_ws;
    float*    lc_ws   = (float*)w;                         size_t off = (size_t)BN * 4;
    unsigned* histc   = (unsigned*)(w + off);              off += (size_t)B * HB * 4;
    float*    hists   = (float*)(w + off);                 off += (size_t)B * HB * 4;
    float*    bpi_val = (float*)(w + off);                 off += (size_t)B * SLICES * 16 * 4;
    int*      bpi_idx = (int*)(w + off);                   off += (size_t)B * SLICES * 16 * 4;
    int*      num_pos = (int*)(w + off);                   off += (size_t)B * 4;
    float*    acc     = (float*)(w + off);                 off += 16;

    // zero hist + counters + accumulators (everything after lc)
    size_t zero_off = (size_t)BN * 4;
    hipMemsetAsync(w + zero_off, 0, off - zero_off, stream);

    dim3 gA(SLICES, B);
    kA_best_prior<<<gA, 256, 0, stream>>>(targets, priors, bpi_val, bpi_idx, N, NOBJ, SLICES, CHUNK);

    dim3 gB((N + 255) / 256, B);
    kB_main<<<gB, 256, 0, stream>>>(loc, conf, targets, priors, bpi_val, bpi_idx,
                                    lc_ws, histc, hists, num_pos, acc, N, NOBJ, C, SLICES);

    kC_topk<<<B, 256, 0, stream>>>(lc_ws, histc, hists, num_pos, acc, N);

    kD_final<<<1, 64, 0, stream>>>(num_pos, acc, out, B);
}

// Round 2
// 369.194 us; speedup vs baseline: 1.1818x; 1.1818x over previous
//
#include <hip/hip_runtime.h>
#include <cstdint>
#include <cstddef>

#define HB 2048          // level-1/2 histogram buckets (11 bits)
#define CMAX 21
#define IOU_T 0.5f
#define VV0 0.1f
#define VV1 0.2f

__device__ __forceinline__ float sl1(float x) {
    float ax = fabsf(x);
    return ax < 1.0f ? 0.5f * x * x : ax - 0.5f;
}

// ---------------- Kernel A: per-truth argmax over prior slices ----------------
__global__ __launch_bounds__(256) void kA_best_prior(
    const float* __restrict__ targets, const float* __restrict__ priors,
    float* __restrict__ bpi_val, int* __restrict__ bpi_idx,
    int N, int NOBJ, int SLICES, int CHUNK)
{
    const int s = blockIdx.x, b = blockIdx.y, t = threadIdx.x;
    __shared__ float tb[16 * 4];
    __shared__ float ta[16];
    __shared__ float rv[16 * 256];
    __shared__ int   ri[16 * 256];

    if (t < 16) {
        if (t < NOBJ) {
            const float* tr = targets + ((size_t)b * NOBJ + t) * 5;
            float x0 = tr[0], y0 = tr[1], x1 = tr[2], y1 = tr[3];
            tb[t * 4 + 0] = x0; tb[t * 4 + 1] = y0;
            tb[t * 4 + 2] = x1; tb[t * 4 + 3] = y1;
            ta[t] = (x1 - x0) * (y1 - y0);
        } else {
            tb[t * 4 + 0] = 0.f; tb[t * 4 + 1] = 0.f;
            tb[t * 4 + 2] = 0.f; tb[t * 4 + 3] = 0.f;
            ta[t] = 0.f;
        }
    }
    __syncthreads();

    float bv[16]; int bi[16];
#pragma unroll
    for (int j = 0; j < 16; j++) { bv[j] = -1.0f; bi[j] = 0x7fffffff; }

    const int start = s * CHUNK;
    const int end = min(start + CHUNK, N);
    for (int i = start + t; i < end; i += 256) {
        float4 p = ((const float4*)priors)[i];
        float bx0 = p.x - p.z * 0.5f, by0 = p.y - p.w * 0.5f;
        float bx1 = p.x + p.z * 0.5f, by1 = p.y + p.w * 0.5f;
        float ab = (bx1 - bx0) * (by1 - by0);
#pragma unroll
        for (int j = 0; j < 16; j++) {
            float iw = fminf(tb[j * 4 + 2], bx1) - fmaxf(tb[j * 4 + 0], bx0);
            float ih = fminf(tb[j * 4 + 3], by1) - fmaxf(tb[j * 4 + 1], by0);
            iw = fmaxf(iw, 0.f); ih = fmaxf(ih, 0.f);
            float inter = iw * ih;
            float iou = inter / (ta[j] + ab - inter);
            if (iou > bv[j] || (iou == bv[j] && i < bi[j])) { bv[j] = iou; bi[j] = i; }
        }
    }
#pragma unroll
    for (int j = 0; j < 16; j++) { rv[j * 256 + t] = bv[j]; ri[j * 256 + t] = bi[j]; }
    __syncthreads();
    for (int st = 128; st >= 1; st >>= 1) {
        if (t < st) {
#pragma unroll
            for (int j = 0; j < 16; j++) {
                float v2 = rv[j * 256 + t + st]; int i2 = ri[j * 256 + t + st];
                float v1 = rv[j * 256 + t];      int i1 = ri[j * 256 + t];
                if (v2 > v1 || (v2 == v1 && i2 < i1)) { rv[j * 256 + t] = v2; ri[j * 256 + t] = i2; }
            }
        }
        __syncthreads();
    }
    if (t < NOBJ) {
        int o = (b * SLICES + s) * 16 + t;
        bpi_val[o] = rv[t * 256];
        bpi_idx[o] = ri[t * 256];
    }
}

// ---------------- Kernel B: match + loss_l + lc + histogram ----------------
__global__ __launch_bounds__(256) void kB_main(
    const float* __restrict__ loc, const float* __restrict__ conf,
    const float* __restrict__ targets, const float* __restrict__ priors,
    const float* __restrict__ bpi_val, const int* __restrict__ bpi_idx,
    float* __restrict__ lc_out, unsigned* __restrict__ g_histc, float* __restrict__ g_hists,
    int* __restrict__ num_pos, float* __restrict__ acc,
    int N, int NOBJ, int C, int SLICES)
{
    const int b = blockIdx.y;
    const int t = threadIdx.x;
    const int i0 = blockIdx.x * 256;
    const int i = i0 + t;
    const int rows = min(256, N - i0);

    __shared__ float conf_s[256 * CMAX];
    __shared__ float tb[16 * 4];
    __shared__ float ta[16];
    __shared__ float tl[16];
    __shared__ int   bpi_s[16];
    __shared__ unsigned hc[HB];
    __shared__ float hs[HB];
    __shared__ float wred[4 * 3];

    for (int q = t; q < HB; q += 256) { hc[q] = 0u; hs[q] = 0.f; }
    if (t < 16) {
        if (t < NOBJ) {
            const float* tr = targets + ((size_t)b * NOBJ + t) * 5;
            float x0 = tr[0], y0 = tr[1], x1 = tr[2], y1 = tr[3];
            tb[t * 4 + 0] = x0; tb[t * 4 + 1] = y0;
            tb[t * 4 + 2] = x1; tb[t * 4 + 3] = y1;
            ta[t] = (x1 - x0) * (y1 - y0);
            tl[t] = tr[4];
            float bv = -1.f; int bi = 0x7fffffff;
            for (int s2 = 0; s2 < SLICES; s2++) {
                int o = (b * SLICES + s2) * 16 + t;
                float v = bpi_val[o]; int idx = bpi_idx[o];
                if (v > bv || (v == bv && idx < bi)) { bv = v; bi = idx; }
            }
            bpi_s[t] = bi;
        } else {
            tb[t * 4 + 0] = 0.f; tb[t * 4 + 1] = 0.f; tb[t * 4 + 2] = 0.f; tb[t * 4 + 3] = 0.f;
            ta[t] = 0.f; tl[t] = 0.f; bpi_s[t] = -1;
        }
    }

    // stage conf slab into LDS, coalesced
    {
        const float* cbase = conf + ((size_t)b * N + i0) * C;
        int nf = rows * C;
        if ((((uintptr_t)cbase) & 15) == 0 && (nf & 3) == 0) {
            const float4* s4 = (const float4*)cbase;
            float4* d4 = (float4*)conf_s;
            int nf4 = nf >> 2;
            for (int v = t; v < nf4; v += 256) d4[v] = s4[v];
        } else {
            for (int v = t; v < nf; v += 256) conf_s[v] = cbase[v];
        }
    }
    __syncthreads();

    float ll = 0.f, plc = 0.f, np = 0.f;
    if (i < N) {
        float4 p = ((const float4*)priors)[i];
        float4 ld = ((const float4*)loc)[(size_t)b * N + i];
        float bx0 = p.x - p.z * 0.5f, by0 = p.y - p.w * 0.5f;
        float bx1 = p.x + p.z * 0.5f, by1 = p.y + p.w * 0.5f;
        float ab = (bx1 - bx0) * (by1 - by0);
        float bto = -1.f; int bti = 0;
        for (int j = 0; j < NOBJ; j++) {
            float iw = fminf(tb[j * 4 + 2], bx1) - fmaxf(tb[j * 4 + 0], bx0);
            float ih = fminf(tb[j * 4 + 3], by1) - fmaxf(tb[j * 4 + 1], by0);
            iw = fmaxf(iw, 0.f); ih = fmaxf(ih, 0.f);
            float inter = iw * ih;
            float iou = inter / (ta[j] + ab - inter);
            if (iou > bto) { bto = iou; bti = j; }   // first-argmax over truths
        }
        for (int j = 0; j < NOBJ; j++)
            if (bpi_s[j] == i) { bto = 2.0f; bti = j; }  // override, last j wins
        bool pos = !(bto < IOU_T);
        if (pos) {
            float mx0 = tb[bti * 4 + 0], my0 = tb[bti * 4 + 1];
            float mx1 = tb[bti * 4 + 2], my1 = tb[bti * 4 + 3];
            float gcx = ((mx0 + mx1) * 0.5f - p.x) / (VV0 * p.z);
            float gcy = ((my0 + my1) * 0.5f - p.y) / (VV0 * p.w);
            float gw = logf((mx1 - mx0) / p.z) / VV1;
            float gh = logf((my1 - my0) / p.w) / VV1;
            ll = sl1(ld.x - gcx) + sl1(ld.y - gcy) + sl1(ld.z - gw) + sl1(ld.w - gh);
            np = 1.f;
        }
        int cf = pos ? ((int)tl[bti] + 1) : 0;
        const float* cr = conf_s + t * CMAX;
        float m = cr[0];
#pragma unroll
        for (int c = 1; c < CMAX; c++) m = fmaxf(m, cr[c]);
        float ssum = 0.f;
#pragma unroll
        for (int c = 0; c < CMAX; c++) ssum += __expf(cr[c] - m);
        float lse = m + __logf(ssum);
        float lossc = lse - cr[cf];
        if (pos) plc = lossc;
        float lcv = pos ? 0.f : lossc;
        lcv = fmaxf(lcv, 0.f);
        lc_out[(size_t)b * N + i] = lcv;
        unsigned u = __float_as_uint(lcv);
        atomicAdd(&hc[u >> 20], 1u);
        atomicAdd(&hs[u >> 20], lcv);
    }

    // wave-level reduction (64 lanes), then cross-wave via tiny LDS
#pragma unroll
    for (int off = 32; off >= 1; off >>= 1) {
        ll  += __shfl_down(ll, off, 64);
        plc += __shfl_down(plc, off, 64);
        np  += __shfl_down(np, off, 64);
    }
    const int wid = t >> 6;
    if ((t & 63) == 0) { wred[wid * 3 + 0] = ll; wred[wid * 3 + 1] = plc; wred[wid * 3 + 2] = np; }
    __syncthreads();
    if (t == 0) {
        float a0 = 0.f, a1 = 0.f, a2 = 0.f;
#pragma unroll
        for (int w = 0; w < 4; w++) { a0 += wred[w * 3 + 0]; a1 += wred[w * 3 + 1]; a2 += wred[w * 3 + 2]; }
        atomicAdd(&acc[0], a0);
        atomicAdd(&acc[1], a1);
        atomicAdd(&num_pos[b], (int)a2);
    }
    for (int q = t; q < HB; q += 256) {
        unsigned c = hc[q];
        if (c) {
            atomicAdd(&g_histc[(size_t)b * HB + q], c);
            atomicAdd(&g_hists[(size_t)b * HB + q], hs[q]);
        }
    }
}

// ---------------- Kernel C: 3-level radix select top-k sum ----------------
__device__ __forceinline__ void suffix_scan(int* cnt, float* sm, int n, int t) {
    for (int d = 1; d < n; d <<= 1) {
        int tc[8]; float ts[8];
        int r = 0;
        for (int q = t; q < n; q += 256, r++) {
            int src = q + d;
            tc[r] = (src < n) ? cnt[src] : 0;
            ts[r] = (src < n) ? sm[src] : 0.f;
        }
        __syncthreads();
        r = 0;
        for (int q = t; q < n; q += 256, r++) { cnt[q] += tc[r]; sm[q] += ts[r]; }
        __syncthreads();
    }
}

__global__ __launch_bounds__(256) void kC_topk(
    const float* __restrict__ lc, const unsigned* __restrict__ g_histc,
    const float* __restrict__ g_hists, const int* __restrict__ num_pos,
    float* __restrict__ acc, int N)
{
    const int b = blockIdx.x, t = threadIdx.x;
    __shared__ int cnt[HB];
    __shared__ float sm[HB];
    __shared__ int s_strad, s_krem;
    __shared__ float s_above;

    int k = min(3 * num_pos[b], N - 1);
    if (k <= 0) return;   // uniform per block

    // ---- Level 1: bits [30:20] ----
    for (int q = t; q < HB; q += 256) { cnt[q] = (int)g_histc[(size_t)b * HB + q]; sm[q] = g_hists[(size_t)b * HB + q]; }
    __syncthreads();
    suffix_scan(cnt, sm, HB, t);
    for (int q = t; q < HB; q += 256) {
        int incl = cnt[q];
        int excl = (q < HB - 1) ? cnt[q + 1] : 0;
        if (excl < k && k <= incl) {
            s_strad = q; s_krem = k - excl;
            s_above = (q < HB - 1) ? sm[q + 1] : 0.f;
        }
    }
    __syncthreads();
    int s1 = s_strad, k2 = s_krem;
    float total = s_above;
    __syncthreads();

    // ---- Level 2: bits [19:9] within bucket s1 ----
    for (int q = t; q < HB; q += 256) { cnt[q] = 0; sm[q] = 0.f; }
    __syncthreads();
    const float* lcb = lc + (size_t)b * N;
    for (int i = t; i < N; i += 256) {
        float v = lcb[i];
        unsigned u = __float_as_uint(v);
        if ((int)(u >> 20) == s1) {
            int q = (int)((u >> 9) & 0x7FF);
            atomicAdd(&cnt[q], 1); atomicAdd(&sm[q], v);
        }
    }
    __syncthreads();
    suffix_scan(cnt, sm, HB, t);
    for (int q = t; q < HB; q += 256) {
        int incl = cnt[q];
        int excl = (q < HB - 1) ? cnt[q + 1] : 0;
        if (excl < k2 && k2 <= incl) {
            s_strad = q; s_krem = k2 - excl;
            s_above = (q < HB - 1) ? sm[q + 1] : 0.f;
        }
    }
    __syncthreads();
    int s2 = s_strad, k3 = s_krem;
    total += s_above;
    __syncthreads();

    // ---- Level 3: bits [8:0] within (s1,s2) ----
    for (int q = t; q < 512; q += 256) { cnt[q] = 0; sm[q] = 0.f; }
    __syncthreads();
    unsigned pref = (((unsigned)s1) << 11) | (unsigned)s2;
    for (int i = t; i < N; i += 256) {
        float v = lcb[i];
        unsigned u = __float_as_uint(v);
        if ((u >> 9) == pref) {
            int q = (int)(u & 0x1FF);
            atomicAdd(&cnt[q], 1); atomicAdd(&sm[q], v);
        }
    }
    __syncthreads();
    suffix_scan(cnt, sm, 512, t);
    for (int q = t; q < 512; q += 256) {
        int incl = cnt[q];
        int excl = (q < 511) ? cnt[q + 1] : 0;
        if (excl < k3 && k3 <= incl) {
            s_strad = q; s_krem = k3 - excl;
            s_above = (q < 511) ? sm[q + 1] : 0.f;
        }
    }
    __syncthreads();
    int s3 = s_strad, krem = s_krem;
    total += s_above;
    float tval = __uint_as_float((((unsigned)s1) << 20) | (((unsigned)s2) << 9) | (unsigned)s3);
    total += (float)krem * tval;
    if (t == 0) atomicAdd(&acc[1], total);
}

// ---------------- Kernel D: finalize (parallel) ----------------
__global__ __launch_bounds__(256) void kD_final(
    const int* __restrict__ num_pos, const float* __restrict__ acc,
    float* __restrict__ out, int B)
{
    const int t = threadIdx.x;
    int v = 0;
    for (int q = t; q < B; q += 256) v += num_pos[q];
#pragma unroll
    for (int off = 32; off >= 1; off >>= 1) v += __shfl_down(v, off, 64);
    __shared__ int wsum[4];
    if ((t & 63) == 0) wsum[t >> 6] = v;
    __syncthreads();
    if (t == 0) {
        float n = (float)(wsum[0] + wsum[1] + wsum[2] + wsum[3]);
        out[0] = acc[0] / n;
        out[1] = acc[1] / n;
    }
}

extern "C" void kernel_launch(void* const* d_in, const int* in_sizes, int n_in,
                              void* d_out, int out_size, void* d_ws, size_t ws_size,
                              hipStream_t stream)
{
    const float* loc     = (const float*)d_in[0];
    const float* conf    = (const float*)d_in[1];
    const float* targets = (const float*)d_in[2];
    const float* priors  = (const float*)d_in[3];
    float* out = (float*)d_out;

    const int N = in_sizes[3] / 4;
    const int BN = in_sizes[0] / 4;
    const int B = BN / N;
    const int C = in_sizes[1] / BN;
    const int NOBJ = in_sizes[2] / (B * 5);
    const int SLICES = 8;
    const int CHUNK = (N + SLICES - 1) / SLICES;

    // workspace layout
    char* w = (char*)d_ws;
    float*    lc_ws   = (float*)w;                         size_t off = (size_t)BN * 4;
    unsigned* histc   = (unsigned*)(w + off);              off += (size_t)B * HB * 4;
    float*    hists   = (float*)(w + off);                 off += (size_t)B * HB * 4;
    float*    bpi_val = (float*)(w + off);                 off += (size_t)B * SLICES * 16 * 4;
    int*      bpi_idx = (int*)(w + off);                   off += (size_t)B * SLICES * 16 * 4;
    int*      num_pos = (int*)(w + off);                   off += (size_t)B * 4;
    float*    acc     = (float*)(w + off);                 off += 16;

    // zero hist + counters + accumulators (everything after lc)
    size_t zero_off = (size_t)BN * 4;
    hipMemsetAsync(w + zero_off, 0, off - zero_off, stream);

    dim3 gA(SLICES, B);
    kA_best_prior<<<gA, 256, 0, stream>>>(targets, priors, bpi_val, bpi_idx, N, NOBJ, SLICES, CHUNK);

    dim3 gB((N + 255) / 256, B);
    kB_main<<<gB, 256, 0, stream>>>(loc, conf, targets, priors, bpi_val, bpi_idx,
                                    lc_ws, histc, hists, num_pos, acc, N, NOBJ, C, SLICES);

    kC_topk<<<B, 256, 0, stream>>>(lc_ws, histc, hists, num_pos, acc, N);

    kD_final<<<1, 256, 0, stream>>>(num_pos, acc, out, B);
}

// Round 3
// 355.337 us; speedup vs baseline: 1.2279x; 1.0390x over previous
//
#include <hip/hip_runtime.h>
#include <cstdint>
#include <cstddef>

#define HB 2048          // radix-select histogram buckets (11 bits)
#define CMAX 21
#define IOU_T 0.5f
#define VV0 0.1f
#define VV1 0.2f

__device__ __forceinline__ float sl1(float x) {
    float ax = fabsf(x);
    return ax < 1.0f ? 0.5f * x * x : ax - 0.5f;
}

// ---------------- Kernel A: per-truth argmax over prior slices ----------------
__global__ __launch_bounds__(256) void kA_best_prior(
    const float* __restrict__ targets, const float* __restrict__ priors,
    float* __restrict__ bpi_val, int* __restrict__ bpi_idx,
    int N, int NOBJ, int SLICES, int CHUNK)
{
    const int s = blockIdx.x, b = blockIdx.y, t = threadIdx.x;
    __shared__ float tb[16 * 4];
    __shared__ float ta[16];
    __shared__ float wv[4 * 16];
    __shared__ int   wi[4 * 16];

    if (t < 16) {
        if (t < NOBJ) {
            const float* tr = targets + ((size_t)b * NOBJ + t) * 5;
            float x0 = tr[0], y0 = tr[1], x1 = tr[2], y1 = tr[3];
            tb[t * 4 + 0] = x0; tb[t * 4 + 1] = y0;
            tb[t * 4 + 2] = x1; tb[t * 4 + 3] = y1;
            ta[t] = (x1 - x0) * (y1 - y0);
        } else {
            tb[t * 4 + 0] = 0.f; tb[t * 4 + 1] = 0.f;
            tb[t * 4 + 2] = 0.f; tb[t * 4 + 3] = 0.f;
            ta[t] = 0.f;
        }
    }
    __syncthreads();

    float bv[16]; int bi[16];
#pragma unroll
    for (int j = 0; j < 16; j++) { bv[j] = -1.0f; bi[j] = 0x7fffffff; }

    const int start = s * CHUNK;
    const int end = min(start + CHUNK, N);
    for (int i = start + t; i < end; i += 256) {
        float4 p = ((const float4*)priors)[i];
        float bx0 = p.x - p.z * 0.5f, by0 = p.y - p.w * 0.5f;
        float bx1 = p.x + p.z * 0.5f, by1 = p.y + p.w * 0.5f;
        float ab = (bx1 - bx0) * (by1 - by0);
#pragma unroll
        for (int j = 0; j < 16; j++) {
            float iw = fminf(tb[j * 4 + 2], bx1) - fmaxf(tb[j * 4 + 0], bx0);
            float ih = fminf(tb[j * 4 + 3], by1) - fmaxf(tb[j * 4 + 1], by0);
            iw = fmaxf(iw, 0.f); ih = fmaxf(ih, 0.f);
            float inter = iw * ih;
            float iou = inter / (ta[j] + ab - inter);
            if (iou > bv[j] || (iou == bv[j] && i < bi[j])) { bv[j] = iou; bi[j] = i; }
        }
    }

    // wave-level argmax reduction via shuffles (tie -> min index)
#pragma unroll
    for (int off = 32; off >= 1; off >>= 1) {
#pragma unroll
        for (int j = 0; j < 16; j++) {
            float v2 = __shfl_down(bv[j], off, 64);
            int   i2 = __shfl_down(bi[j], off, 64);
            if (v2 > bv[j] || (v2 == bv[j] && i2 < bi[j])) { bv[j] = v2; bi[j] = i2; }
        }
    }
    const int wid = t >> 6, lane = t & 63;
    if (lane == 0) {
#pragma unroll
        for (int j = 0; j < 16; j++) { wv[wid * 16 + j] = bv[j]; wi[wid * 16 + j] = bi[j]; }
    }
    __syncthreads();
    if (t < 16) {
        float v = wv[t]; int idx = wi[t];
#pragma unroll
        for (int w = 1; w < 4; w++) {
            float v2 = wv[w * 16 + t]; int i2 = wi[w * 16 + t];
            if (v2 > v || (v2 == v && i2 < idx)) { v = v2; idx = i2; }
        }
        if (t < NOBJ) {
            int o = (b * SLICES + s) * 16 + t;
            bpi_val[o] = v;
            bpi_idx[o] = idx;
        }
    }
}

// ---------------- Kernel B: match + loss_l + lc ----------------
__global__ __launch_bounds__(256) void kB_main(
    const float* __restrict__ loc, const float* __restrict__ conf,
    const float* __restrict__ targets, const float* __restrict__ priors,
    const float* __restrict__ bpi_val, const int* __restrict__ bpi_idx,
    float* __restrict__ lc_out, int* __restrict__ num_pos, float* __restrict__ acc,
    int N, int NOBJ, int C, int SLICES)
{
    const int b = blockIdx.y;
    const int t = threadIdx.x;
    const int i0 = blockIdx.x * 256;
    const int i = i0 + t;
    const int rows = min(256, N - i0);

    __shared__ __align__(16) float conf_s[256 * CMAX];
    __shared__ float tb[16 * 4];
    __shared__ float ta[16];
    __shared__ float tl[16];
    __shared__ int   bpi_s[16];
    __shared__ float wred[4 * 3];

    if (t < 16) {
        if (t < NOBJ) {
            const float* tr = targets + ((size_t)b * NOBJ + t) * 5;
            float x0 = tr[0], y0 = tr[1], x1 = tr[2], y1 = tr[3];
            tb[t * 4 + 0] = x0; tb[t * 4 + 1] = y0;
            tb[t * 4 + 2] = x1; tb[t * 4 + 3] = y1;
            ta[t] = (x1 - x0) * (y1 - y0);
            tl[t] = tr[4];
            float bv = -1.f; int bi = 0x7fffffff;
            for (int s2 = 0; s2 < SLICES; s2++) {
                int o = (b * SLICES + s2) * 16 + t;
                float v = bpi_val[o]; int idx = bpi_idx[o];
                if (v > bv || (v == bv && idx < bi)) { bv = v; bi = idx; }
            }
            bpi_s[t] = bi;
        } else {
            tb[t * 4 + 0] = 0.f; tb[t * 4 + 1] = 0.f; tb[t * 4 + 2] = 0.f; tb[t * 4 + 3] = 0.f;
            ta[t] = 0.f; tl[t] = 0.f; bpi_s[t] = -1;
        }
    }

    // stage conf slab into LDS via async global->LDS (16B per lane per issue)
    {
        const float* cbase = conf + ((size_t)b * N + i0) * C;
        int nf = rows * C;
        if ((((uintptr_t)cbase) & 15) == 0 && (nf & 3) == 0) {
            const float4* s4 = (const float4*)cbase;
            int nf4 = nf >> 2;
            const int wid = t >> 6, lane = t & 63;
            for (int base = wid * 64; base < nf4; base += 256) {
                int idx = base + lane;
                if (idx < nf4) {
                    __builtin_amdgcn_global_load_lds(
                        (const __attribute__((address_space(1))) void*)(s4 + idx),
                        (__attribute__((address_space(3))) void*)(conf_s + (size_t)base * 4),
                        16, 0, 0);
                }
            }
        } else {
            for (int v = t; v < nf; v += 256) conf_s[v] = cbase[v];
        }
    }
    __syncthreads();

    float ll = 0.f, plc = 0.f, np = 0.f;
    if (i < N) {
        float4 p = ((const float4*)priors)[i];
        float4 ld = ((const float4*)loc)[(size_t)b * N + i];
        float bx0 = p.x - p.z * 0.5f, by0 = p.y - p.w * 0.5f;
        float bx1 = p.x + p.z * 0.5f, by1 = p.y + p.w * 0.5f;
        float ab = (bx1 - bx0) * (by1 - by0);
        float bto = -1.f; int bti = 0;
        for (int j = 0; j < NOBJ; j++) {
            float iw = fminf(tb[j * 4 + 2], bx1) - fmaxf(tb[j * 4 + 0], bx0);
            float ih = fminf(tb[j * 4 + 3], by1) - fmaxf(tb[j * 4 + 1], by0);
            iw = fmaxf(iw, 0.f); ih = fmaxf(ih, 0.f);
            float inter = iw * ih;
            float iou = inter / (ta[j] + ab - inter);
            if (iou > bto) { bto = iou; bti = j; }   // first-argmax over truths
        }
        for (int j = 0; j < NOBJ; j++)
            if (bpi_s[j] == i) { bto = 2.0f; bti = j; }  // override, last j wins
        bool pos = !(bto < IOU_T);
        if (pos) {
            float mx0 = tb[bti * 4 + 0], my0 = tb[bti * 4 + 1];
            float mx1 = tb[bti * 4 + 2], my1 = tb[bti * 4 + 3];
            float gcx = ((mx0 + mx1) * 0.5f - p.x) / (VV0 * p.z);
            float gcy = ((my0 + my1) * 0.5f - p.y) / (VV0 * p.w);
            float gw = logf((mx1 - mx0) / p.z) / VV1;
            float gh = logf((my1 - my0) / p.w) / VV1;
            ll = sl1(ld.x - gcx) + sl1(ld.y - gcy) + sl1(ld.z - gw) + sl1(ld.w - gh);
            np = 1.f;
        }
        int cf = pos ? ((int)tl[bti] + 1) : 0;
        const float* cr = conf_s + t * CMAX;
        float m = cr[0];
#pragma unroll
        for (int c = 1; c < CMAX; c++) m = fmaxf(m, cr[c]);
        float ssum = 0.f;
#pragma unroll
        for (int c = 0; c < CMAX; c++) ssum += __expf(cr[c] - m);
        float lse = m + __logf(ssum);
        float lossc = lse - cr[cf];
        if (pos) plc = lossc;
        float lcv = pos ? 0.f : lossc;
        lcv = fmaxf(lcv, 0.f);
        lc_out[(size_t)b * N + i] = lcv;
    }

    // wave-level reduction, then cross-wave via tiny LDS
#pragma unroll
    for (int off = 32; off >= 1; off >>= 1) {
        ll  += __shfl_down(ll, off, 64);
        plc += __shfl_down(plc, off, 64);
        np  += __shfl_down(np, off, 64);
    }
    const int wid2 = t >> 6;
    if ((t & 63) == 0) { wred[wid2 * 3 + 0] = ll; wred[wid2 * 3 + 1] = plc; wred[wid2 * 3 + 2] = np; }
    __syncthreads();
    if (t == 0) {
        float a0 = 0.f, a1 = 0.f, a2 = 0.f;
#pragma unroll
        for (int w = 0; w < 4; w++) { a0 += wred[w * 3 + 0]; a1 += wred[w * 3 + 1]; a2 += wred[w * 3 + 2]; }
        atomicAdd(&acc[0], a0);
        atomicAdd(&acc[1], a1);
        atomicAdd(&num_pos[b], (int)a2);
    }
}

// ---------------- Kernel C: 3-level radix select top-k sum ----------------
__device__ __forceinline__ void suffix_scan(int* cnt, float* sm, int n, int t) {
    for (int d = 1; d < n; d <<= 1) {
        int tc[8]; float ts[8];
        int r = 0;
        for (int q = t; q < n; q += 256, r++) {
            int src = q + d;
            tc[r] = (src < n) ? cnt[src] : 0;
            ts[r] = (src < n) ? sm[src] : 0.f;
        }
        __syncthreads();
        r = 0;
        for (int q = t; q < n; q += 256, r++) { cnt[q] += tc[r]; sm[q] += ts[r]; }
        __syncthreads();
    }
}

__global__ __launch_bounds__(256) void kC_topk(
    const float* __restrict__ lc, const int* __restrict__ num_pos,
    float* __restrict__ acc, int N)
{
    const int b = blockIdx.x, t = threadIdx.x;
    __shared__ int cnt[HB];
    __shared__ float sm[HB];
    __shared__ int s_strad, s_krem;
    __shared__ float s_above;

    int k = min(3 * num_pos[b], N - 1);
    if (k <= 0) return;   // uniform per block

    const float* lcb = lc + (size_t)b * N;

    // ---- Level 1: bits [30:20], histogram built from lc scan ----
    for (int q = t; q < HB; q += 256) { cnt[q] = 0; sm[q] = 0.f; }
    __syncthreads();
    for (int i = t; i < N; i += 256) {
        float v = lcb[i];
        unsigned u = __float_as_uint(v);
        atomicAdd(&cnt[u >> 20], 1); atomicAdd(&sm[u >> 20], v);
    }
    __syncthreads();
    suffix_scan(cnt, sm, HB, t);
    for (int q = t; q < HB; q += 256) {
        int incl = cnt[q];
        int excl = (q < HB - 1) ? cnt[q + 1] : 0;
        if (excl < k && k <= incl) {
            s_strad = q; s_krem = k - excl;
            s_above = (q < HB - 1) ? sm[q + 1] : 0.f;
        }
    }
    __syncthreads();
    int s1 = s_strad, k2 = s_krem;
    float total = s_above;
    __syncthreads();

    // ---- Level 2: bits [19:9] within bucket s1 ----
    for (int q = t; q < HB; q += 256) { cnt[q] = 0; sm[q] = 0.f; }
    __syncthreads();
    for (int i = t; i < N; i += 256) {
        float v = lcb[i];
        unsigned u = __float_as_uint(v);
        if ((int)(u >> 20) == s1) {
            int q = (int)((u >> 9) & 0x7FF);
            atomicAdd(&cnt[q], 1); atomicAdd(&sm[q], v);
        }
    }
    __syncthreads();
    suffix_scan(cnt, sm, HB, t);
    for (int q = t; q < HB; q += 256) {
        int incl = cnt[q];
        int excl = (q < HB - 1) ? cnt[q + 1] : 0;
        if (excl < k2 && k2 <= incl) {
            s_strad = q; s_krem = k2 - excl;
            s_above = (q < HB - 1) ? sm[q + 1] : 0.f;
        }
    }
    __syncthreads();
    int s2 = s_strad, k3 = s_krem;
    total += s_above;
    __syncthreads();

    // ---- Level 3: bits [8:0] within (s1,s2) ----
    for (int q = t; q < 512; q += 256) { cnt[q] = 0; sm[q] = 0.f; }
    __syncthreads();
    unsigned pref = (((unsigned)s1) << 11) | (unsigned)s2;
    for (int i = t; i < N; i += 256) {
        float v = lcb[i];
        unsigned u = __float_as_uint(v);
        if ((u >> 9) == pref) {
            int q = (int)(u & 0x1FF);
            atomicAdd(&cnt[q], 1); atomicAdd(&sm[q], v);
        }
    }
    __syncthreads();
    suffix_scan(cnt, sm, 512, t);
    for (int q = t; q < 512; q += 256) {
        int incl = cnt[q];
        int excl = (q < 511) ? cnt[q + 1] : 0;
        if (excl < k3 && k3 <= incl) {
            s_strad = q; s_krem = k3 - excl;
            s_above = (q < 511) ? sm[q + 1] : 0.f;
        }
    }
    __syncthreads();
    int s3 = s_strad, krem = s_krem;
    total += s_above;
    float tval = __uint_as_float((((unsigned)s1) << 20) | (((unsigned)s2) << 9) | (unsigned)s3);
    total += (float)krem * tval;
    if (t == 0) atomicAdd(&acc[1], total);
}

// ---------------- Kernel D: finalize (parallel) ----------------
__global__ __launch_bounds__(256) void kD_final(
    const int* __restrict__ num_pos, const float* __restrict__ acc,
    float* __restrict__ out, int B)
{
    const int t = threadIdx.x;
    int v = 0;
    for (int q = t; q < B; q += 256) v += num_pos[q];
#pragma unroll
    for (int off = 32; off >= 1; off >>= 1) v += __shfl_down(v, off, 64);
    __shared__ int wsum[4];
    if ((t & 63) == 0) wsum[t >> 6] = v;
    __syncthreads();
    if (t == 0) {
        float n = (float)(wsum[0] + wsum[1] + wsum[2] + wsum[3]);
        out[0] = acc[0] / n;
        out[1] = acc[1] / n;
    }
}

extern "C" void kernel_launch(void* const* d_in, const int* in_sizes, int n_in,
                              void* d_out, int out_size, void* d_ws, size_t ws_size,
                              hipStream_t stream)
{
    const float* loc     = (const float*)d_in[0];
    const float* conf    = (const float*)d_in[1];
    const float* targets = (const float*)d_in[2];
    const float* priors  = (const float*)d_in[3];
    float* out = (float*)d_out;

    const int N = in_sizes[3] / 4;
    const int BN = in_sizes[0] / 4;
    const int B = BN / N;
    const int C = in_sizes[1] / BN;
    const int NOBJ = in_sizes[2] / (B * 5);
    const int SLICES = 8;
    const int CHUNK = (N + SLICES - 1) / SLICES;

    // workspace layout
    char* w = (char*)d_ws;
    float*    lc_ws   = (float*)w;                         size_t off = (size_t)BN * 4;
    float*    bpi_val = (float*)(w + off);                 off += (size_t)B * SLICES * 16 * 4;
    int*      bpi_idx = (int*)(w + off);                   off += (size_t)B * SLICES * 16 * 4;
    size_t zero_off = off;
    int*      num_pos = (int*)(w + off);                   off += (size_t)B * 4;
    float*    acc     = (float*)(w + off);                 off += 16;

    // zero counters + accumulators only
    hipMemsetAsync(w + zero_off, 0, off - zero_off, stream);

    dim3 gA(SLICES, B);
    kA_best_prior<<<gA, 256, 0, stream>>>(targets, priors, bpi_val, bpi_idx, N, NOBJ, SLICES, CHUNK);

    dim3 gB((N + 255) / 256, B);
    kB_main<<<gB, 256, 0, stream>>>(loc, conf, targets, priors, bpi_val, bpi_idx,
                                    lc_ws, num_pos, acc, N, NOBJ, C, SLICES);

    kC_topk<<<B, 256, 0, stream>>>(lc_ws, num_pos, acc, N);

    kD_final<<<1, 256, 0, stream>>>(num_pos, acc, out, B);
}

// Round 4
// 326.896 us; speedup vs baseline: 1.3347x; 1.0870x over previous
//
#include <hip/hip_runtime.h>
#include <cstdint>
#include <cstddef>

#define HB 2048          // radix-select histogram buckets (11 bits)
#define CMAX 21
#define IOU_T 0.5f
#define VV0 0.1f
#define VV1 0.2f

__device__ __forceinline__ float sl1(float x) {
    float ax = fabsf(x);
    return ax < 1.0f ? 0.5f * x * x : ax - 0.5f;
}

// ---------------- Kernel A: per-truth argmax over prior slices (+ zero-init fold) ----------------
__global__ __launch_bounds__(256) void kA_best_prior(
    const float* __restrict__ targets, const float* __restrict__ priors,
    float* __restrict__ bpi_val, int* __restrict__ bpi_idx,
    int* __restrict__ num_pos_g, float* __restrict__ acc_g, unsigned* __restrict__ done_g,
    int N, int NOBJ, int SLICES, int CHUNK, int B)
{
    const int s = blockIdx.x, b = blockIdx.y, t = threadIdx.x;
    __shared__ float tb[16 * 4];
    __shared__ float ta[16];
    __shared__ float wv[4 * 16];
    __shared__ int   wi[4 * 16];

    // fold: zero counters/accumulators once (block 0,0)
    if (s == 0 && b == 0) {
        for (int q = t; q < B; q += 256) num_pos_g[q] = 0;
        if (t < 4) acc_g[t] = 0.f;
        if (t == 0) *done_g = 0u;
    }

    if (t < 16) {
        if (t < NOBJ) {
            const float* tr = targets + ((size_t)b * NOBJ + t) * 5;
            float x0 = tr[0], y0 = tr[1], x1 = tr[2], y1 = tr[3];
            tb[t * 4 + 0] = x0; tb[t * 4 + 1] = y0;
            tb[t * 4 + 2] = x1; tb[t * 4 + 3] = y1;
            ta[t] = (x1 - x0) * (y1 - y0);
        } else {
            tb[t * 4 + 0] = 0.f; tb[t * 4 + 1] = 0.f;
            tb[t * 4 + 2] = 0.f; tb[t * 4 + 3] = 0.f;
            ta[t] = 0.f;
        }
    }
    __syncthreads();

    float bv[16]; int bi[16];
#pragma unroll
    for (int j = 0; j < 16; j++) { bv[j] = -1.0f; bi[j] = 0x7fffffff; }

    const int start = s * CHUNK;
    const int end = min(start + CHUNK, N);
    for (int i = start + t; i < end; i += 256) {
        float4 p = ((const float4*)priors)[i];
        float bx0 = p.x - p.z * 0.5f, by0 = p.y - p.w * 0.5f;
        float bx1 = p.x + p.z * 0.5f, by1 = p.y + p.w * 0.5f;
        float ab = (bx1 - bx0) * (by1 - by0);
#pragma unroll
        for (int j = 0; j < 16; j++) {
            float iw = fminf(tb[j * 4 + 2], bx1) - fmaxf(tb[j * 4 + 0], bx0);
            float ih = fminf(tb[j * 4 + 3], by1) - fmaxf(tb[j * 4 + 1], by0);
            iw = fmaxf(iw, 0.f); ih = fmaxf(ih, 0.f);
            float inter = iw * ih;
            float iou = inter / (ta[j] + ab - inter);
            if (iou > bv[j] || (iou == bv[j] && i < bi[j])) { bv[j] = iou; bi[j] = i; }
        }
    }

    // wave-level argmax reduction via shuffles (tie -> min index)
#pragma unroll
    for (int off = 32; off >= 1; off >>= 1) {
#pragma unroll
        for (int j = 0; j < 16; j++) {
            float v2 = __shfl_down(bv[j], off, 64);
            int   i2 = __shfl_down(bi[j], off, 64);
            if (v2 > bv[j] || (v2 == bv[j] && i2 < bi[j])) { bv[j] = v2; bi[j] = i2; }
        }
    }
    const int wid = t >> 6, lane = t & 63;
    if (lane == 0) {
#pragma unroll
        for (int j = 0; j < 16; j++) { wv[wid * 16 + j] = bv[j]; wi[wid * 16 + j] = bi[j]; }
    }
    __syncthreads();
    if (t < 16) {
        float v = wv[t]; int idx = wi[t];
#pragma unroll
        for (int w = 1; w < 4; w++) {
            float v2 = wv[w * 16 + t]; int i2 = wi[w * 16 + t];
            if (v2 > v || (v2 == v && i2 < idx)) { v = v2; idx = i2; }
        }
        if (t < NOBJ) {
            int o = (b * SLICES + s) * 16 + t;
            bpi_val[o] = v;
            bpi_idx[o] = idx;
        }
    }
}

// ---------------- Kernel B: match + loss_l + lc (per-wave async staging, no post-stage barrier) ----------------
__global__ __launch_bounds__(256) void kB_main(
    const float* __restrict__ loc, const float* __restrict__ conf,
    const float* __restrict__ targets, const float* __restrict__ priors,
    const float* __restrict__ bpi_val, const int* __restrict__ bpi_idx,
    float* __restrict__ lc_out, int* __restrict__ num_pos, float* __restrict__ acc,
    int N, int NOBJ, int C, int SLICES)
{
    const int b = blockIdx.y;
    const int t = threadIdx.x;
    const int i0 = blockIdx.x * 256;
    const int i = i0 + t;
    const int wid = t >> 6, lane = t & 63;

    __shared__ __align__(16) float conf_s[256 * CMAX];
    __shared__ __align__(16) float tb[16 * 4];
    __shared__ float tl[16];
    __shared__ __align__(16) int bpi_s[16];
    __shared__ float wred[4 * 3];

    if (t < 16) {
        if (t < NOBJ) {
            const float* tr = targets + ((size_t)b * NOBJ + t) * 5;
            tb[t * 4 + 0] = tr[0]; tb[t * 4 + 1] = tr[1];
            tb[t * 4 + 2] = tr[2]; tb[t * 4 + 3] = tr[3];
            tl[t] = tr[4];
            float bv = -1.f; int bi = 0x7fffffff;
            for (int s2 = 0; s2 < SLICES; s2++) {
                int o = (b * SLICES + s2) * 16 + t;
                float v = bpi_val[o]; int idx = bpi_idx[o];
                if (v > bv || (v == bv && idx < bi)) { bv = v; bi = idx; }
            }
            bpi_s[t] = bi;
        } else {
            tb[t * 4 + 0] = 0.f; tb[t * 4 + 1] = 0.f; tb[t * 4 + 2] = 0.f; tb[t * 4 + 3] = 0.f;
            tl[t] = 0.f; bpi_s[t] = -1;
        }
    }
    __syncthreads();   // only barrier before compute: tb/tl/bpi_s ready

    // per-wave async stage of this wave's 64 rows into its own LDS segment
    const int row0 = i0 + wid * 64;
    const int wrows = min(64, N - row0);
    if (wrows > 0) {
        const float* cbase = conf + ((size_t)b * N + row0) * CMAX;   // 16B-aligned by construction
        const int nf = wrows * CMAX;
        const int nf4 = nf >> 2;
        float* ldsbase = conf_s + wid * 64 * CMAX;
        const float4* s4 = (const float4*)cbase;
        for (int j = 0; j * 64 < nf4; ++j) {
            int idx = j * 64 + lane;
            if (idx < nf4) {
                __builtin_amdgcn_global_load_lds(
                    (const __attribute__((address_space(1))) void*)(s4 + idx),
                    (__attribute__((address_space(3))) void*)(ldsbase + j * 256),
                    16, 0, 0);
            }
        }
        int rem = nf - (nf4 << 2);
        if (lane < rem) ldsbase[(nf4 << 2) + lane] = cbase[(nf4 << 2) + lane];
        asm volatile("s_waitcnt vmcnt(0)" ::: "memory");   // wave-local drain, no block barrier
    }

    float ll = 0.f, plc = 0.f, np = 0.f;
    if (i < N) {
        float4 p = ((const float4*)priors)[i];
        float4 ld = ((const float4*)loc)[(size_t)b * N + i];
        float bx0 = p.x - p.z * 0.5f, by0 = p.y - p.w * 0.5f;
        float bx1 = p.x + p.z * 0.5f, by1 = p.y + p.w * 0.5f;
        float ab = (bx1 - bx0) * (by1 - by0);
        float bto = -1.f; int bti = 0;
        const float4* tb4 = (const float4*)tb;
        for (int j = 0; j < NOBJ; j++) {
            float4 tj = tb4[j];                       // one ds_read_b128 broadcast
            float taj = (tj.z - tj.x) * (tj.w - tj.y);
            float iw = fminf(tj.z, bx1) - fmaxf(tj.x, bx0);
            float ih = fminf(tj.w, by1) - fmaxf(tj.y, by0);
            iw = fmaxf(iw, 0.f); ih = fmaxf(ih, 0.f);
            float inter = iw * ih;
            float iou = inter / (taj + ab - inter);
            if (iou > bto) { bto = iou; bti = j; }    // first-argmax over truths
        }
        const int4* bp4 = (const int4*)bpi_s;
#pragma unroll
        for (int jj = 0; jj < 4; jj++) {              // override, last j wins
            int4 q = bp4[jj];
            if (q.x == i) { bto = 2.0f; bti = jj * 4 + 0; }
            if (q.y == i) { bto = 2.0f; bti = jj * 4 + 1; }
            if (q.z == i) { bto = 2.0f; bti = jj * 4 + 2; }
            if (q.w == i) { bto = 2.0f; bti = jj * 4 + 3; }
        }
        bool pos = !(bto < IOU_T);
        if (pos) {
            float4 tj = tb4[bti];
            float gcx = ((tj.x + tj.z) * 0.5f - p.x) / (VV0 * p.z);
            float gcy = ((tj.y + tj.w) * 0.5f - p.y) / (VV0 * p.w);
            float gw = logf((tj.z - tj.x) / p.z) / VV1;
            float gh = logf((tj.w - tj.y) / p.w) / VV1;
            ll = sl1(ld.x - gcx) + sl1(ld.y - gcy) + sl1(ld.z - gw) + sl1(ld.w - gh);
            np = 1.f;
        }
        int cf = pos ? ((int)tl[bti] + 1) : 0;
        const float* cr = conf_s + t * CMAX;
        float m = cr[0];
#pragma unroll
        for (int c = 1; c < CMAX; c++) m = fmaxf(m, cr[c]);
        float ssum = 0.f;
#pragma unroll
        for (int c = 0; c < CMAX; c++) ssum += __expf(cr[c] - m);
        float lse = m + __logf(ssum);
        float lossc = lse - cr[cf];
        if (pos) plc = lossc;
        float lcv = pos ? 0.f : lossc;
        lcv = fmaxf(lcv, 0.f);
        lc_out[(size_t)b * N + i] = lcv;
    }

    // wave-level reduction, then cross-wave via tiny LDS
#pragma unroll
    for (int off = 32; off >= 1; off >>= 1) {
        ll  += __shfl_down(ll, off, 64);
        plc += __shfl_down(plc, off, 64);
        np  += __shfl_down(np, off, 64);
    }
    if (lane == 0) { wred[wid * 3 + 0] = ll; wred[wid * 3 + 1] = plc; wred[wid * 3 + 2] = np; }
    __syncthreads();
    if (t == 0) {
        float a0 = 0.f, a1 = 0.f, a2 = 0.f;
#pragma unroll
        for (int w = 0; w < 4; w++) { a0 += wred[w * 3 + 0]; a1 += wred[w * 3 + 1]; a2 += wred[w * 3 + 2]; }
        atomicAdd(&acc[0], a0);
        atomicAdd(&acc[1], a1);
        atomicAdd(&num_pos[b], (int)a2);
    }
}

// ---------------- Kernel C: 3-level radix select top-k sum (+ finalize fold) ----------------
__device__ __forceinline__ void suffix_scan(int* cnt, float* sm, int n, int t, int nt) {
    for (int d = 1; d < n; d <<= 1) {
        int tc[4]; float ts[4];
        int r = 0;
        for (int q = t; q < n; q += nt, r++) {
            int src = q + d;
            tc[r] = (src < n) ? cnt[src] : 0;
            ts[r] = (src < n) ? sm[src] : 0.f;
        }
        __syncthreads();
        r = 0;
        for (int q = t; q < n; q += nt, r++) { cnt[q] += tc[r]; sm[q] += ts[r]; }
        __syncthreads();
    }
}

__global__ __launch_bounds__(512) void kC_topk(
    const float* __restrict__ lc, const int* __restrict__ num_pos,
    float* __restrict__ acc, unsigned* __restrict__ done_ctr,
    float* __restrict__ out, int N, int B)
{
    const int b = blockIdx.x, t = threadIdx.x;
    const int NT = 512;
    __shared__ int cnt[HB];
    __shared__ float sm[HB];
    __shared__ int s_strad, s_krem;
    __shared__ float s_above;
    __shared__ int s_last;
    __shared__ int wsum[8];

    const int k = min(3 * num_pos[b], N - 1);
    const float* lcb = lc + (size_t)b * N;
    float total = 0.f;

    if (k > 0) {
        // ---- Level 1: bits [30:20] ----
        for (int q = t; q < HB; q += NT) { cnt[q] = 0; sm[q] = 0.f; }
        __syncthreads();
        for (int i = t; i < N; i += 4 * NT) {
            float v0 = lcb[i];
            float v1 = (i + NT     < N) ? lcb[i + NT]     : -1.f;
            float v2 = (i + 2 * NT < N) ? lcb[i + 2 * NT] : -1.f;
            float v3 = (i + 3 * NT < N) ? lcb[i + 3 * NT] : -1.f;
            { unsigned u = __float_as_uint(v0); atomicAdd(&cnt[u >> 20], 1); atomicAdd(&sm[u >> 20], v0); }
            if (v1 >= 0.f) { unsigned u = __float_as_uint(v1); atomicAdd(&cnt[u >> 20], 1); atomicAdd(&sm[u >> 20], v1); }
            if (v2 >= 0.f) { unsigned u = __float_as_uint(v2); atomicAdd(&cnt[u >> 20], 1); atomicAdd(&sm[u >> 20], v2); }
            if (v3 >= 0.f) { unsigned u = __float_as_uint(v3); atomicAdd(&cnt[u >> 20], 1); atomicAdd(&sm[u >> 20], v3); }
        }
        __syncthreads();
        suffix_scan(cnt, sm, HB, t, NT);
        for (int q = t; q < HB; q += NT) {
            int incl = cnt[q];
            int excl = (q < HB - 1) ? cnt[q + 1] : 0;
            if (excl < k && k <= incl) {
                s_strad = q; s_krem = k - excl;
                s_above = (q < HB - 1) ? sm[q + 1] : 0.f;
            }
        }
        __syncthreads();
        int s1 = s_strad, k2 = s_krem;
        total += s_above;
        __syncthreads();

        // ---- Level 2: bits [19:9] within bucket s1 ----
        for (int q = t; q < HB; q += NT) { cnt[q] = 0; sm[q] = 0.f; }
        __syncthreads();
        for (int i = t; i < N; i += NT) {
            float v = lcb[i];
            unsigned u = __float_as_uint(v);
            if ((int)(u >> 20) == s1) {
                int q = (int)((u >> 9) & 0x7FF);
                atomicAdd(&cnt[q], 1); atomicAdd(&sm[q], v);
            }
        }
        __syncthreads();
        suffix_scan(cnt, sm, HB, t, NT);
        for (int q = t; q < HB; q += NT) {
            int incl = cnt[q];
            int excl = (q < HB - 1) ? cnt[q + 1] : 0;
            if (excl < k2 && k2 <= incl) {
                s_strad = q; s_krem = k2 - excl;
                s_above = (q < HB - 1) ? sm[q + 1] : 0.f;
            }
        }
        __syncthreads();
        int s2 = s_strad, k3 = s_krem;
        total += s_above;
        __syncthreads();

        // ---- Level 3: bits [8:0] within (s1,s2) ----
        for (int q = t; q < 512; q += NT) { cnt[q] = 0; sm[q] = 0.f; }
        __syncthreads();
        unsigned pref = (((unsigned)s1) << 11) | (unsigned)s2;
        for (int i = t; i < N; i += NT) {
            float v = lcb[i];
            unsigned u = __float_as_uint(v);
            if ((u >> 9) == pref) {
                int q = (int)(u & 0x1FF);
                atomicAdd(&cnt[q], 1); atomicAdd(&sm[q], v);
            }
        }
        __syncthreads();
        suffix_scan(cnt, sm, 512, t, NT);
        for (int q = t; q < 512; q += NT) {
            int incl = cnt[q];
            int excl = (q < 511) ? cnt[q + 1] : 0;
            if (excl < k3 && k3 <= incl) {
                s_strad = q; s_krem = k3 - excl;
                s_above = (q < 511) ? sm[q + 1] : 0.f;
            }
        }
        __syncthreads();
        int s3 = s_strad, krem = s_krem;
        total += s_above;
        float tval = __uint_as_float((((unsigned)s1) << 20) | (((unsigned)s2) << 9) | (unsigned)s3);
        total += (float)krem * tval;
    }

    // contribute + last-block finalize (replaces kD)
    if (t == 0) {
        if (k > 0) atomicAdd(&acc[1], total);
        __threadfence();
        unsigned old = atomicAdd(done_ctr, 1u);
        s_last = (old == (unsigned)gridDim.x - 1u) ? 1 : 0;
    }
    __syncthreads();
    if (s_last) {
        __threadfence();
        int v = 0;
        for (int q = t; q < B; q += NT) v += num_pos[q];
#pragma unroll
        for (int off = 32; off >= 1; off >>= 1) v += __shfl_down(v, off, 64);
        if ((t & 63) == 0) wsum[t >> 6] = v;
        __syncthreads();
        if (t == 0) {
            int nt_ = 0;
#pragma unroll
            for (int w = 0; w < 8; w++) nt_ += wsum[w];
            float n = (float)nt_;
            float l2 = atomicAdd(&acc[1], 0.0f);   // device-scope read of concurrent accumulator
            out[0] = acc[0] / n;
            out[1] = l2 / n;
        }
    }
}

extern "C" void kernel_launch(void* const* d_in, const int* in_sizes, int n_in,
                              void* d_out, int out_size, void* d_ws, size_t ws_size,
                              hipStream_t stream)
{
    const float* loc     = (const float*)d_in[0];
    const float* conf    = (const float*)d_in[1];
    const float* targets = (const float*)d_in[2];
    const float* priors  = (const float*)d_in[3];
    float* out = (float*)d_out;

    const int N = in_sizes[3] / 4;
    const int BN = in_sizes[0] / 4;
    const int B = BN / N;
    const int C = in_sizes[1] / BN;
    const int NOBJ = in_sizes[2] / (B * 5);
    const int SLICES = 8;
    const int CHUNK = (N + SLICES - 1) / SLICES;

    // workspace layout
    char* w = (char*)d_ws;
    float*    lc_ws   = (float*)w;                         size_t off = (size_t)BN * 4;
    float*    bpi_val = (float*)(w + off);                 off += (size_t)B * SLICES * 16 * 4;
    int*      bpi_idx = (int*)(w + off);                   off += (size_t)B * SLICES * 16 * 4;
    int*      num_pos = (int*)(w + off);                   off += (size_t)B * 4;
    float*    acc     = (float*)(w + off);                 off += 16;
    unsigned* done    = (unsigned*)(w + off);              off += 16;

    dim3 gA(SLICES, B);
    kA_best_prior<<<gA, 256, 0, stream>>>(targets, priors, bpi_val, bpi_idx,
                                          num_pos, acc, done, N, NOBJ, SLICES, CHUNK, B);

    dim3 gB((N + 255) / 256, B);
    kB_main<<<gB, 256, 0, stream>>>(loc, conf, targets, priors, bpi_val, bpi_idx,
                                    lc_ws, num_pos, acc, N, NOBJ, C, SLICES);

    kC_topk<<<B, 512, 0, stream>>>(lc_ws, num_pos, acc, done, out, N, B);
}

// Round 5
// 318.392 us; speedup vs baseline: 1.3703x; 1.0267x over previous
//
#include <hip/hip_runtime.h>
#include <cstdint>
#include <cstddef>

#define HB 2048          // radix-select histogram buckets (11 bits)
#define CMAX 21
#define IOU_T 0.5f
#define VV0 0.1f
#define VV1 0.2f

__device__ __forceinline__ float sl1(float x) {
    float ax = fabsf(x);
    return ax < 1.0f ? 0.5f * x * x : ax - 0.5f;
}

// ---------------- Kernel A: per-truth argmax over prior slices (+ zero-init fold) ----------------
__global__ __launch_bounds__(256) void kA_best_prior(
    const float* __restrict__ targets, const float* __restrict__ priors,
    float* __restrict__ bpi_val, int* __restrict__ bpi_idx,
    int* __restrict__ num_pos_g, float* __restrict__ accB_g,
    float* __restrict__ acc_g, unsigned* __restrict__ done_g,
    int N, int NOBJ, int SLICES, int CHUNK, int B)
{
    const int s = blockIdx.x, b = blockIdx.y, t = threadIdx.x;
    __shared__ float tb[16 * 4];
    __shared__ float ta[16];
    __shared__ float wv[4 * 16];
    __shared__ int   wi[4 * 16];

    // fold: zero counters/accumulators once (block 0,0)
    if (s == 0 && b == 0) {
        for (int q = t; q < B; q += 256) num_pos_g[q] = 0;
        for (int q = t; q < 2 * B; q += 256) accB_g[q] = 0.f;
        if (t < 4) acc_g[t] = 0.f;
        if (t == 0) *done_g = 0u;
    }

    if (t < 16) {
        if (t < NOBJ) {
            const float* tr = targets + ((size_t)b * NOBJ + t) * 5;
            float x0 = tr[0], y0 = tr[1], x1 = tr[2], y1 = tr[3];
            tb[t * 4 + 0] = x0; tb[t * 4 + 1] = y0;
            tb[t * 4 + 2] = x1; tb[t * 4 + 3] = y1;
            ta[t] = (x1 - x0) * (y1 - y0);
        } else {
            tb[t * 4 + 0] = 0.f; tb[t * 4 + 1] = 0.f;
            tb[t * 4 + 2] = 0.f; tb[t * 4 + 3] = 0.f;
            ta[t] = 0.f;
        }
    }
    __syncthreads();

    float bv[16]; int bi[16];
#pragma unroll
    for (int j = 0; j < 16; j++) { bv[j] = -1.0f; bi[j] = 0x7fffffff; }

    const int start = s * CHUNK;
    const int end = min(start + CHUNK, N);
    for (int i = start + t; i < end; i += 256) {
        float4 p = ((const float4*)priors)[i];
        float bx0 = p.x - p.z * 0.5f, by0 = p.y - p.w * 0.5f;
        float bx1 = p.x + p.z * 0.5f, by1 = p.y + p.w * 0.5f;
        float ab = (bx1 - bx0) * (by1 - by0);
#pragma unroll
        for (int j = 0; j < 16; j++) {
            float iw = fminf(tb[j * 4 + 2], bx1) - fmaxf(tb[j * 4 + 0], bx0);
            float ih = fminf(tb[j * 4 + 3], by1) - fmaxf(tb[j * 4 + 1], by0);
            iw = fmaxf(iw, 0.f); ih = fmaxf(ih, 0.f);
            float inter = iw * ih;
            float iou = inter / (ta[j] + ab - inter);
            if (iou > bv[j] || (iou == bv[j] && i < bi[j])) { bv[j] = iou; bi[j] = i; }
        }
    }

    // wave-level argmax reduction via shuffles (tie -> min index)
#pragma unroll
    for (int off = 32; off >= 1; off >>= 1) {
#pragma unroll
        for (int j = 0; j < 16; j++) {
            float v2 = __shfl_down(bv[j], off, 64);
            int   i2 = __shfl_down(bi[j], off, 64);
            if (v2 > bv[j] || (v2 == bv[j] && i2 < bi[j])) { bv[j] = v2; bi[j] = i2; }
        }
    }
    const int wid = t >> 6, lane = t & 63;
    if (lane == 0) {
#pragma unroll
        for (int j = 0; j < 16; j++) { wv[wid * 16 + j] = bv[j]; wi[wid * 16 + j] = bi[j]; }
    }
    __syncthreads();
    if (t < 16) {
        float v = wv[t]; int idx = wi[t];
#pragma unroll
        for (int w = 1; w < 4; w++) {
            float v2 = wv[w * 16 + t]; int i2 = wi[w * 16 + t];
            if (v2 > v || (v2 == v && i2 < idx)) { v = v2; idx = i2; }
        }
        if (t < NOBJ) {
            int o = (b * SLICES + s) * 16 + t;
            bpi_val[o] = v;
            bpi_idx[o] = idx;
        }
    }
}

// ---------------- Kernel B: match + loss_l + lc — 128-thread blocks, high TLP ----------------
#define IOU_STEP(j) { \
    float4 tj = tb4[j]; \
    float taj = (tj.z - tj.x) * (tj.w - tj.y); \
    float iw = fminf(tj.z, bx1) - fmaxf(tj.x, bx0); \
    float ih = fminf(tj.w, by1) - fmaxf(tj.y, by0); \
    iw = fmaxf(iw, 0.f); ih = fmaxf(ih, 0.f); \
    float inter = iw * ih; \
    float iou = inter * __builtin_amdgcn_rcpf(taj + ab - inter); \
    if (iou > bto) { bto = iou; bti = (j); } }

__global__ __launch_bounds__(128, 8) void kB_main(
    const float* __restrict__ loc, const float* __restrict__ conf,
    const float* __restrict__ targets, const float* __restrict__ priors,
    const float* __restrict__ bpi_val, const int* __restrict__ bpi_idx,
    float* __restrict__ lc_out, int* __restrict__ num_pos, float* __restrict__ accB,
    int N, int NOBJ, int SLICES)
{
    const int b = blockIdx.y;
    const int t = threadIdx.x;
    const int i0 = blockIdx.x * 128;
    const int i = i0 + t;
    const int wid = t >> 6, lane = t & 63;

    __shared__ __align__(16) float conf_s[128 * CMAX];   // 10752 B
    __shared__ __align__(16) float tb[16 * 4];
    __shared__ float tl[16];
    __shared__ __align__(16) int bpi_s[16];

    // prefix: lanes 0..15 of wave 0 load truth metadata + merge best-prior
    if (t < 16) {
        if (t < NOBJ) {
            const float* tr = targets + ((size_t)b * NOBJ + t) * 5;
            tb[t * 4 + 0] = tr[0]; tb[t * 4 + 1] = tr[1];
            tb[t * 4 + 2] = tr[2]; tb[t * 4 + 3] = tr[3];
            tl[t] = tr[4];
            float bv = -1.f; int bi = 0x7fffffff;
#pragma unroll
            for (int s2 = 0; s2 < 8; s2++) {
                if (s2 < SLICES) {
                    int o = (b * SLICES + s2) * 16 + t;
                    float v = bpi_val[o]; int idx = bpi_idx[o];
                    if (v > bv || (v == bv && idx < bi)) { bv = v; bi = idx; }
                }
            }
            bpi_s[t] = bi;
        } else {
            tb[t * 4 + 0] = 0.f; tb[t * 4 + 1] = 0.f; tb[t * 4 + 2] = 0.f; tb[t * 4 + 3] = 0.f;
            tl[t] = 0.f; bpi_s[t] = -1;
        }
    }

    // per-wave async stage of this wave's 64 rows into its own LDS segment
    const int row0 = i0 + wid * 64;
    const int wrows = min(64, N - row0);
    if (wrows > 0) {
        const float* cbase = conf + ((size_t)b * N + row0) * CMAX;
        const int nf = wrows * CMAX;
        const int nf4 = nf >> 2;
        float* ldsbase = conf_s + wid * 64 * CMAX;
        const float4* s4 = (const float4*)cbase;
        for (int j = 0; j * 64 < nf4; ++j) {
            int idx = j * 64 + lane;
            if (idx < nf4) {
                __builtin_amdgcn_global_load_lds(
                    (const __attribute__((address_space(1))) void*)(s4 + idx),
                    (__attribute__((address_space(3))) void*)(ldsbase + j * 256),
                    16, 0, 0);
            }
        }
        int rem = nf & 3;
        if (lane < rem) ldsbase[(nf4 << 2) + lane] = cbase[(nf4 << 2) + lane];
    }
    asm volatile("s_waitcnt vmcnt(0)" ::: "memory");
    __syncthreads();

    float ll = 0.f, plc = 0.f, np = 0.f;
    if (i < N) {
        float4 p = ((const float4*)priors)[i];
        float4 ld = ((const float4*)loc)[(size_t)b * N + i];
        float bx0 = p.x - p.z * 0.5f, by0 = p.y - p.w * 0.5f;
        float bx1 = p.x + p.z * 0.5f, by1 = p.y + p.w * 0.5f;
        float ab = (bx1 - bx0) * (by1 - by0);
        float bto = -1.f; int bti = 0;
        const float4* tb4 = (const float4*)tb;
        if (NOBJ == 16) {
#pragma unroll
            for (int j = 0; j < 16; j++) IOU_STEP(j);
        } else {
            for (int j = 0; j < NOBJ; j++) IOU_STEP(j);
        }
        const int4* bp4 = (const int4*)bpi_s;
#pragma unroll
        for (int jj = 0; jj < 4; jj++) {              // override, last j wins
            int4 q = bp4[jj];
            if (q.x == i) { bto = 2.0f; bti = jj * 4 + 0; }
            if (q.y == i) { bto = 2.0f; bti = jj * 4 + 1; }
            if (q.z == i) { bto = 2.0f; bti = jj * 4 + 2; }
            if (q.w == i) { bto = 2.0f; bti = jj * 4 + 3; }
        }
        bool pos = !(bto < IOU_T);
        if (pos) {
            float4 tj = tb4[bti];
            float rz = __builtin_amdgcn_rcpf(p.z);
            float rw = __builtin_amdgcn_rcpf(p.w);
            float gcx = ((tj.x + tj.z) * 0.5f - p.x) * (10.0f * rz);
            float gcy = ((tj.y + tj.w) * 0.5f - p.y) * (10.0f * rw);
            float gw = __logf((tj.z - tj.x) * rz) * 5.0f;
            float gh = __logf((tj.w - tj.y) * rw) * 5.0f;
            ll = sl1(ld.x - gcx) + sl1(ld.y - gcy) + sl1(ld.z - gw) + sl1(ld.w - gh);
            np = 1.f;
        }
        int cf = pos ? ((int)tl[bti] + 1) : 0;
        const float* cr = conf_s + t * CMAX;
        float m = cr[0];
#pragma unroll
        for (int c = 1; c < CMAX; c++) m = fmaxf(m, cr[c]);
        float ssum = 0.f;
#pragma unroll
        for (int c = 0; c < CMAX; c++) ssum += __expf(cr[c] - m);
        float lse = m + __logf(ssum);
        float lossc = lse - cr[cf];
        if (pos) plc = lossc;
        float lcv = pos ? 0.f : lossc;
        lcv = fmaxf(lcv, 0.f);
        lc_out[(size_t)b * N + i] = lcv;
    }

    // wave-level reduction; each wave's lane 0 atomics to per-batch accumulators
#pragma unroll
    for (int off = 32; off >= 1; off >>= 1) {
        ll  += __shfl_down(ll, off, 64);
        plc += __shfl_down(plc, off, 64);
        np  += __shfl_down(np, off, 64);
    }
    if (lane == 0) {
        atomicAdd(&accB[b * 2 + 0], ll);
        atomicAdd(&accB[b * 2 + 1], plc);
        atomicAdd(&num_pos[b], (int)np);
    }
}

// ---------------- Kernel C: 3-level radix select top-k sum (+ finalize fold) ----------------
__device__ __forceinline__ void suffix_scan(int* cnt, float* sm, int n, int t, int nt) {
    for (int d = 1; d < n; d <<= 1) {
        int tc[4]; float ts[4];
        int r = 0;
        for (int q = t; q < n; q += nt, r++) {
            int src = q + d;
            tc[r] = (src < n) ? cnt[src] : 0;
            ts[r] = (src < n) ? sm[src] : 0.f;
        }
        __syncthreads();
        r = 0;
        for (int q = t; q < n; q += nt, r++) { cnt[q] += tc[r]; sm[q] += ts[r]; }
        __syncthreads();
    }
}

__global__ __launch_bounds__(512) void kC_topk(
    const float* __restrict__ lc, const int* __restrict__ num_pos,
    const float* __restrict__ accB,
    float* __restrict__ acc, unsigned* __restrict__ done_ctr,
    float* __restrict__ out, int N, int B)
{
    const int b = blockIdx.x, t = threadIdx.x;
    const int NT = 512;
    __shared__ int cnt[HB];
    __shared__ float sm[HB];
    __shared__ int s_strad, s_krem;
    __shared__ float s_above;
    __shared__ int s_last;
    __shared__ float wsum[8], wsA[8], wsB[8];

    const int k = min(3 * num_pos[b], N - 1);
    const float* lcb = lc + (size_t)b * N;
    float total = 0.f;

    if (k > 0) {
        // ---- Level 1: bits [30:20], float4 scan ----
        for (int q = t; q < HB; q += NT) { cnt[q] = 0; sm[q] = 0.f; }
        __syncthreads();
        const int n4 = N >> 2;
        const float4* lcb4 = (const float4*)lcb;
        for (int i = t; i < n4; i += NT) {
            float4 v = lcb4[i];
            { unsigned u = __float_as_uint(v.x); atomicAdd(&cnt[u >> 20], 1); atomicAdd(&sm[u >> 20], v.x); }
            { unsigned u = __float_as_uint(v.y); atomicAdd(&cnt[u >> 20], 1); atomicAdd(&sm[u >> 20], v.y); }
            { unsigned u = __float_as_uint(v.z); atomicAdd(&cnt[u >> 20], 1); atomicAdd(&sm[u >> 20], v.z); }
            { unsigned u = __float_as_uint(v.w); atomicAdd(&cnt[u >> 20], 1); atomicAdd(&sm[u >> 20], v.w); }
        }
        for (int i = (n4 << 2) + t; i < N; i += NT) {
            float v = lcb[i];
            unsigned u = __float_as_uint(v);
            atomicAdd(&cnt[u >> 20], 1); atomicAdd(&sm[u >> 20], v);
        }
        __syncthreads();
        suffix_scan(cnt, sm, HB, t, NT);
        for (int q = t; q < HB; q += NT) {
            int incl = cnt[q];
            int excl = (q < HB - 1) ? cnt[q + 1] : 0;
            if (excl < k && k <= incl) {
                s_strad = q; s_krem = k - excl;
                s_above = (q < HB - 1) ? sm[q + 1] : 0.f;
            }
        }
        __syncthreads();
        int s1 = s_strad, k2 = s_krem;
        total += s_above;
        __syncthreads();

        // ---- Level 2: bits [19:9] within bucket s1 ----
        for (int q = t; q < HB; q += NT) { cnt[q] = 0; sm[q] = 0.f; }
        __syncthreads();
        for (int i = t; i < N; i += NT) {
            float v = lcb[i];
            unsigned u = __float_as_uint(v);
            if ((int)(u >> 20) == s1) {
                int q = (int)((u >> 9) & 0x7FF);
                atomicAdd(&cnt[q], 1); atomicAdd(&sm[q], v);
            }
        }
        __syncthreads();
        suffix_scan(cnt, sm, HB, t, NT);
        for (int q = t; q < HB; q += NT) {
            int incl = cnt[q];
            int excl = (q < HB - 1) ? cnt[q + 1] : 0;
            if (excl < k2 && k2 <= incl) {
                s_strad = q; s_krem = k2 - excl;
                s_above = (q < HB - 1) ? sm[q + 1] : 0.f;
            }
        }
        __syncthreads();
        int s2 = s_strad, k3 = s_krem;
        total += s_above;
        __syncthreads();

        // ---- Level 3: bits [8:0] within (s1,s2) ----
        for (int q = t; q < 512; q += NT) { cnt[q] = 0; sm[q] = 0.f; }
        __syncthreads();
        unsigned pref = (((unsigned)s1) << 11) | (unsigned)s2;
        for (int i = t; i < N; i += NT) {
            float v = lcb[i];
            unsigned u = __float_as_uint(v);
            if ((u >> 9) == pref) {
                int q = (int)(u & 0x1FF);
                atomicAdd(&cnt[q], 1); atomicAdd(&sm[q], v);
            }
        }
        __syncthreads();
        suffix_scan(cnt, sm, 512, t, NT);
        for (int q = t; q < 512; q += NT) {
            int incl = cnt[q];
            int excl = (q < 511) ? cnt[q + 1] : 0;
            if (excl < k3 && k3 <= incl) {
                s_strad = q; s_krem = k3 - excl;
                s_above = (q < 511) ? sm[q + 1] : 0.f;
            }
        }
        __syncthreads();
        int s3 = s_strad, krem = s_krem;
        total += s_above;
        float tval = __uint_as_float((((unsigned)s1) << 20) | (((unsigned)s2) << 9) | (unsigned)s3);
        total += (float)krem * tval;
    }

    // contribute + last-block finalize
    if (t == 0) {
        if (k > 0) atomicAdd(&acc[1], total);
        __threadfence();
        unsigned old = atomicAdd(done_ctr, 1u);
        s_last = (old == (unsigned)gridDim.x - 1u) ? 1 : 0;
    }
    __syncthreads();
    if (s_last) {
        __threadfence();
        float vn = 0.f, va = 0.f, vb = 0.f;
        for (int q = t; q < B; q += NT) {
            vn += (float)num_pos[q];
            va += accB[q * 2 + 0];
            vb += accB[q * 2 + 1];
        }
#pragma unroll
        for (int off = 32; off >= 1; off >>= 1) {
            vn += __shfl_down(vn, off, 64);
            va += __shfl_down(va, off, 64);
            vb += __shfl_down(vb, off, 64);
        }
        if ((t & 63) == 0) { wsum[t >> 6] = vn; wsA[t >> 6] = va; wsB[t >> 6] = vb; }
        __syncthreads();
        if (t == 0) {
            float n = 0.f, a = 0.f, bsum = 0.f;
#pragma unroll
            for (int w = 0; w < 8; w++) { n += wsum[w]; a += wsA[w]; bsum += wsB[w]; }
            float l2 = atomicAdd(&acc[1], 0.0f);   // all kC contributions visible (done_ctr ordering)
            out[0] = a / n;
            out[1] = (bsum + l2) / n;
        }
    }
}

extern "C" void kernel_launch(void* const* d_in, const int* in_sizes, int n_in,
                              void* d_out, int out_size, void* d_ws, size_t ws_size,
                              hipStream_t stream)
{
    const float* loc     = (const float*)d_in[0];
    const float* conf    = (const float*)d_in[1];
    const float* targets = (const float*)d_in[2];
    const float* priors  = (const float*)d_in[3];
    float* out = (float*)d_out;

    const int N = in_sizes[3] / 4;
    const int BN = in_sizes[0] / 4;
    const int B = BN / N;
    const int NOBJ = in_sizes[2] / (B * 5);
    const int SLICES = 8;
    const int CHUNK = (N + SLICES - 1) / SLICES;

    // workspace layout
    char* w = (char*)d_ws;
    float*    lc_ws   = (float*)w;                         size_t off = (size_t)BN * 4;
    float*    bpi_val = (float*)(w + off);                 off += (size_t)B * SLICES * 16 * 4;
    int*      bpi_idx = (int*)(w + off);                   off += (size_t)B * SLICES * 16 * 4;
    int*      num_pos = (int*)(w + off);                   off += (size_t)B * 4;
    float*    accB    = (float*)(w + off);                 off += (size_t)B * 2 * 4;
    float*    acc     = (float*)(w + off);                 off += 16;
    unsigned* done    = (unsigned*)(w + off);              off += 16;

    dim3 gA(SLICES, B);
    kA_best_prior<<<gA, 256, 0, stream>>>(targets, priors, bpi_val, bpi_idx,
                                          num_pos, accB, acc, done, N, NOBJ, SLICES, CHUNK, B);

    dim3 gB((N + 127) / 128, B);
    kB_main<<<gB, 128, 0, stream>>>(loc, conf, targets, priors, bpi_val, bpi_idx,
                                    lc_ws, num_pos, accB, N, NOBJ, SLICES);

    kC_topk<<<B, 512, 0, stream>>>(lc_ws, num_pos, accB, acc, done, out, N, B);
}

// Round 6
// 261.179 us; speedup vs baseline: 1.6705x; 1.2191x over previous
//
#include <hip/hip_runtime.h>
#include <cstdint>
#include <cstddef>

#define HB1 4096         // kC level-1 buckets (u>>19)
#define HB2 2048         // kC level-2 buckets ((u>>8)&0x7FF)
#define CMAX 21
#define IOU_T 0.5f

__device__ __forceinline__ float sl1(float x) {
    float ax = fabsf(x);
    return ax < 1.0f ? 0.5f * x * x : ax - 0.5f;
}

// ---------------- Kernel A: per-truth argmax over prior slices (+ zero-init fold) ----------------
__global__ __launch_bounds__(256) void kA_best_prior(
    const float* __restrict__ targets, const float* __restrict__ priors,
    float* __restrict__ bpi_val, int* __restrict__ bpi_idx,
    int* __restrict__ num_pos_g, float* __restrict__ accB_g,
    float* __restrict__ acc_g, unsigned* __restrict__ done_g,
    int N, int NOBJ, int SLICES, int CHUNK, int B)
{
    const int s = blockIdx.x, b = blockIdx.y, t = threadIdx.x;
    __shared__ float tb[16 * 4];
    __shared__ float ta[16];
    __shared__ float wv[4 * 16];
    __shared__ int   wi[4 * 16];

    if (s == 0 && b == 0) {
        for (int q = t; q < B; q += 256) num_pos_g[q] = 0;
        for (int q = t; q < 2 * B; q += 256) accB_g[q] = 0.f;
        if (t < 4) acc_g[t] = 0.f;
        if (t == 0) *done_g = 0u;
    }

    if (t < 16) {
        if (t < NOBJ) {
            const float* tr = targets + ((size_t)b * NOBJ + t) * 5;
            float x0 = tr[0], y0 = tr[1], x1 = tr[2], y1 = tr[3];
            tb[t * 4 + 0] = x0; tb[t * 4 + 1] = y0;
            tb[t * 4 + 2] = x1; tb[t * 4 + 3] = y1;
            ta[t] = (x1 - x0) * (y1 - y0);
        } else {
            tb[t * 4 + 0] = 0.f; tb[t * 4 + 1] = 0.f;
            tb[t * 4 + 2] = 0.f; tb[t * 4 + 3] = 0.f;
            ta[t] = 0.f;
        }
    }
    __syncthreads();

    float bv[16]; int bi[16];
#pragma unroll
    for (int j = 0; j < 16; j++) { bv[j] = -1.0f; bi[j] = 0x7fffffff; }

    const int start = s * CHUNK;
    const int end = min(start + CHUNK, N);
    for (int i = start + t; i < end; i += 256) {
        float4 p = ((const float4*)priors)[i];
        float bx0 = p.x - p.z * 0.5f, by0 = p.y - p.w * 0.5f;
        float bx1 = p.x + p.z * 0.5f, by1 = p.y + p.w * 0.5f;
        float ab = (bx1 - bx0) * (by1 - by0);
#pragma unroll
        for (int j = 0; j < 16; j++) {
            float iw = fminf(tb[j * 4 + 2], bx1) - fmaxf(tb[j * 4 + 0], bx0);
            float ih = fminf(tb[j * 4 + 3], by1) - fmaxf(tb[j * 4 + 1], by0);
            iw = fmaxf(iw, 0.f); ih = fmaxf(ih, 0.f);
            float inter = iw * ih;
            float iou = inter / (ta[j] + ab - inter);
            if (iou > bv[j] || (iou == bv[j] && i < bi[j])) { bv[j] = iou; bi[j] = i; }
        }
    }

#pragma unroll
    for (int off = 32; off >= 1; off >>= 1) {
#pragma unroll
        for (int j = 0; j < 16; j++) {
            float v2 = __shfl_down(bv[j], off, 64);
            int   i2 = __shfl_down(bi[j], off, 64);
            if (v2 > bv[j] || (v2 == bv[j] && i2 < bi[j])) { bv[j] = v2; bi[j] = i2; }
        }
    }
    const int wid = t >> 6, lane = t & 63;
    if (lane == 0) {
#pragma unroll
        for (int j = 0; j < 16; j++) { wv[wid * 16 + j] = bv[j]; wi[wid * 16 + j] = bi[j]; }
    }
    __syncthreads();
    if (t < 16) {
        float v = wv[t]; int idx = wi[t];
#pragma unroll
        for (int w = 1; w < 4; w++) {
            float v2 = wv[w * 16 + t]; int i2 = wi[w * 16 + t];
            if (v2 > v || (v2 == v && i2 < idx)) { v = v2; idx = i2; }
        }
        if (t < NOBJ) {
            int o = (b * SLICES + s) * 16 + t;
            bpi_val[o] = v;
            bpi_idx[o] = idx;
        }
    }
}

// ---------------- Kernel B: software-pipelined multi-tile (reg-staged double-buffered LDS) ----------------
#define IOU_STEP(j) { \
    float4 tj = tb4[j]; \
    float taj = (tj.z - tj.x) * (tj.w - tj.y); \
    float iw = fminf(tj.z, bx1) - fmaxf(tj.x, bx0); \
    float ih = fminf(tj.w, by1) - fmaxf(tj.y, by0); \
    iw = fmaxf(iw, 0.f); ih = fmaxf(ih, 0.f); \
    float inter = iw * ih; \
    float iou = inter * __builtin_amdgcn_rcpf(taj + ab - inter); \
    if (iou > bto) { bto = iou; bti = (j); } }

__global__ __launch_bounds__(256, 3) void kB_main(
    const float* __restrict__ loc, const float* __restrict__ conf,
    const float* __restrict__ targets, const float* __restrict__ priors,
    const float* __restrict__ bpi_val, const int* __restrict__ bpi_idx,
    float* __restrict__ lc_out, int* __restrict__ num_pos, float* __restrict__ accB,
    int N, int NOBJ, int SLICES, int TPB, int BPB)
{
    const int g = blockIdx.x;
    const int b = g / BPB;
    const int j0 = g % BPB;
    const int t = threadIdx.x;
    const int wid = t >> 6, lane = t & 63;

    __shared__ __align__(16) float buf[2][256 * CMAX];   // 2 x 21504 B
    __shared__ __align__(16) float tb[16 * 4];
    __shared__ float tl[16];
    __shared__ __align__(16) int bpi_s[16];
    __shared__ float wred[4 * 3];

    // prefix: truth metadata + best-prior merge (visible after first loop barrier)
    if (t < 16) {
        if (t < NOBJ) {
            const float* tr = targets + ((size_t)b * NOBJ + t) * 5;
            tb[t * 4 + 0] = tr[0]; tb[t * 4 + 1] = tr[1];
            tb[t * 4 + 2] = tr[2]; tb[t * 4 + 3] = tr[3];
            tl[t] = tr[4];
            float bv = -1.f; int bi = 0x7fffffff;
            for (int s2 = 0; s2 < SLICES; s2++) {
                int o = (b * SLICES + s2) * 16 + t;
                float v = bpi_val[o]; int idx = bpi_idx[o];
                if (v > bv || (v == bv && idx < bi)) { bv = v; bi = idx; }
            }
            bpi_s[t] = bi;
        } else {
            tb[t * 4 + 0] = 0.f; tb[t * 4 + 1] = 0.f; tb[t * 4 + 2] = 0.f; tb[t * 4 + 3] = 0.f;
            tl[t] = 0.f; bpi_s[t] = -1;
        }
    }

    const float* confB = conf + (size_t)b * N * CMAX;
    const float* locB  = loc + (size_t)b * N * 4;

    float4 r0, r1, r2, r3, r4, r5, pld, ppr;

    // stage tile x's conf slab + this thread's loc/priors row into registers (issue only)
    auto stage = [&](int xx) {
        int i0s = xx * 256;
        int rows_s = min(256, N - i0s);
        int nf4s = (rows_s * CMAX) >> 2;
        const float4* s4 = (const float4*)(confB + (size_t)i0s * CMAX);
        if (t + 0    < nf4s) r0 = s4[t + 0];
        if (t + 256  < nf4s) r1 = s4[t + 256];
        if (t + 512  < nf4s) r2 = s4[t + 512];
        if (t + 768  < nf4s) r3 = s4[t + 768];
        if (t + 1024 < nf4s) r4 = s4[t + 1024];
        if (t + 1280 < nf4s) r5 = s4[t + 1280];
        if (t < rows_s) {
            ppr = ((const float4*)priors)[i0s + t];
            pld = ((const float4*)locB)[i0s + t];
        }
    };

    float ll = 0.f, plc = 0.f, np = 0.f;
    int x = j0, p = 0;
    if (x < TPB) stage(x);

    while (x < TPB) {
        const int i0 = x * 256;
        const int rows = min(256, N - i0);
        const int nf4 = (rows * CMAX) >> 2;

        float4 myp = ppr, myl = pld;   // snapshot before restage

        // drain staged regs into LDS buffer p
        float4* bp4f = (float4*)buf[p];
        if (t + 0    < nf4) bp4f[t + 0]    = r0;
        if (t + 256  < nf4) bp4f[t + 256]  = r1;
        if (t + 512  < nf4) bp4f[t + 512]  = r2;
        if (t + 768  < nf4) bp4f[t + 768]  = r3;
        if (t + 1024 < nf4) bp4f[t + 1024] = r4;
        if (t + 1280 < nf4) bp4f[t + 1280] = r5;
        __syncthreads();

        int xn = x + BPB;
        if (xn < TPB) stage(xn);     // issue next tile's loads; latency hidden by compute below

        if (t < rows) {
            const int i = i0 + t;
            float4 pp = myp;
            float bx0 = pp.x - pp.z * 0.5f, by0 = pp.y - pp.w * 0.5f;
            float bx1 = pp.x + pp.z * 0.5f, by1 = pp.y + pp.w * 0.5f;
            float ab = (bx1 - bx0) * (by1 - by0);
            float bto = -1.f; int bti = 0;
            const float4* tb4 = (const float4*)tb;
            if (NOBJ == 16) {
#pragma unroll
                for (int j = 0; j < 16; j++) IOU_STEP(j);
            } else {
                for (int j = 0; j < NOBJ; j++) IOU_STEP(j);
            }
            const int4* bp4 = (const int4*)bpi_s;
#pragma unroll
            for (int jj = 0; jj < 4; jj++) {          // override, last j wins
                int4 q = bp4[jj];
                if (q.x == i) { bto = 2.0f; bti = jj * 4 + 0; }
                if (q.y == i) { bto = 2.0f; bti = jj * 4 + 1; }
                if (q.z == i) { bto = 2.0f; bti = jj * 4 + 2; }
                if (q.w == i) { bto = 2.0f; bti = jj * 4 + 3; }
            }
            bool pos = !(bto < IOU_T);
            if (pos) {
                float4 tj = tb4[bti];
                float rz = __builtin_amdgcn_rcpf(pp.z);
                float rw = __builtin_amdgcn_rcpf(pp.w);
                float gcx = ((tj.x + tj.z) * 0.5f - pp.x) * (10.0f * rz);
                float gcy = ((tj.y + tj.w) * 0.5f - pp.y) * (10.0f * rw);
                float gw = __logf((tj.z - tj.x) * rz) * 5.0f;
                float gh = __logf((tj.w - tj.y) * rw) * 5.0f;
                ll += sl1(myl.x - gcx) + sl1(myl.y - gcy) + sl1(myl.z - gw) + sl1(myl.w - gh);
                np += 1.f;
            }
            int cf = pos ? ((int)tl[bti] + 1) : 0;
            const float* cr = buf[p] + t * CMAX;
            float m = cr[0];
#pragma unroll
            for (int c = 1; c < CMAX; c++) m = fmaxf(m, cr[c]);
            float ssum = 0.f;
#pragma unroll
            for (int c = 0; c < CMAX; c++) ssum += __expf(cr[c] - m);
            float lse = m + __logf(ssum);
            float lossc = lse - cr[cf];
            if (pos) plc += lossc;
            float lcv = pos ? 0.f : lossc;
            lcv = fmaxf(lcv, 0.f);
            lc_out[(size_t)b * N + i] = lcv;
        }
        p ^= 1;
        x = xn;
    }

    // block reduction, 3 atomics per block
#pragma unroll
    for (int off = 32; off >= 1; off >>= 1) {
        ll  += __shfl_down(ll, off, 64);
        plc += __shfl_down(plc, off, 64);
        np  += __shfl_down(np, off, 64);
    }
    if (lane == 0) { wred[wid * 3 + 0] = ll; wred[wid * 3 + 1] = plc; wred[wid * 3 + 2] = np; }
    __syncthreads();
    if (t == 0) {
        float a0 = 0.f, a1 = 0.f, a2 = 0.f;
#pragma unroll
        for (int w = 0; w < 4; w++) { a0 += wred[w * 3 + 0]; a1 += wred[w * 3 + 1]; a2 += wred[w * 3 + 2]; }
        atomicAdd(&accB[b * 2 + 0], a0);
        atomicAdd(&accB[b * 2 + 1], a1);
        atomicAdd(&num_pos[b], (int)a2);
    }
}

// ---------------- Kernel C: 2-level radix select top-k sum (+ finalize fold) ----------------
__device__ __forceinline__ void suffix_scan(int* cnt, float* sm, int n, int t, int nt) {
    for (int d = 1; d < n; d <<= 1) {
        int tc[8]; float ts[8];
        int r = 0;
        for (int q = t; q < n; q += nt, r++) {
            int src = q + d;
            tc[r] = (src < n) ? cnt[src] : 0;
            ts[r] = (src < n) ? sm[src] : 0.f;
        }
        __syncthreads();
        r = 0;
        for (int q = t; q < n; q += nt, r++) { cnt[q] += tc[r]; sm[q] += ts[r]; }
        __syncthreads();
    }
}

__global__ __launch_bounds__(512) void kC_topk(
    const float* __restrict__ lc, const int* __restrict__ num_pos,
    const float* __restrict__ accB,
    float* __restrict__ acc, unsigned* __restrict__ done_ctr,
    float* __restrict__ out, int N, int B)
{
    const int b = blockIdx.x, t = threadIdx.x;
    const int NT = 512;
    __shared__ int cnt[HB1];
    __shared__ float sm[HB1];
    __shared__ int s_strad, s_krem;
    __shared__ float s_above;
    __shared__ int s_last;
    __shared__ float wsum[8], wsA[8], wsB[8];

    const int k = min(3 * num_pos[b], N - 1);
    const float* lcb = lc + (size_t)b * N;
    float total = 0.f;

    if (k > 0) {
        // ---- Level 1: bits [30:19] (4096 buckets) ----
        for (int q = t; q < HB1; q += NT) { cnt[q] = 0; sm[q] = 0.f; }
        __syncthreads();
        const int n4 = N >> 2;
        const float4* lcb4 = (const float4*)lcb;
        for (int i = t; i < n4; i += NT) {
            float4 v = lcb4[i];
            { unsigned u = __float_as_uint(v.x) >> 19; atomicAdd(&cnt[u], 1); atomicAdd(&sm[u], v.x); }
            { unsigned u = __float_as_uint(v.y) >> 19; atomicAdd(&cnt[u], 1); atomicAdd(&sm[u], v.y); }
            { unsigned u = __float_as_uint(v.z) >> 19; atomicAdd(&cnt[u], 1); atomicAdd(&sm[u], v.z); }
            { unsigned u = __float_as_uint(v.w) >> 19; atomicAdd(&cnt[u], 1); atomicAdd(&sm[u], v.w); }
        }
        for (int i = (n4 << 2) + t; i < N; i += NT) {
            float v = lcb[i];
            unsigned u = __float_as_uint(v) >> 19;
            atomicAdd(&cnt[u], 1); atomicAdd(&sm[u], v);
        }
        __syncthreads();
        suffix_scan(cnt, sm, HB1, t, NT);
        for (int q = t; q < HB1; q += NT) {
            int incl = cnt[q];
            int excl = (q < HB1 - 1) ? cnt[q + 1] : 0;
            if (excl < k && k <= incl) {
                s_strad = q; s_krem = k - excl;
                s_above = (q < HB1 - 1) ? sm[q + 1] : 0.f;
            }
        }
        __syncthreads();
        int s1 = s_strad, k2 = s_krem;
        total += s_above;
        __syncthreads();

        // ---- Level 2: bits [18:8] (2048 buckets) within L1 bucket s1 ----
        for (int q = t; q < HB2; q += NT) { cnt[q] = 0; sm[q] = 0.f; }
        __syncthreads();
        for (int i = t; i < N; i += NT) {
            float v = lcb[i];
            unsigned u = __float_as_uint(v);
            if ((int)(u >> 19) == s1) {
                int q = (int)((u >> 8) & 0x7FF);
                atomicAdd(&cnt[q], 1); atomicAdd(&sm[q], v);
            }
        }
        __syncthreads();
        suffix_scan(cnt, sm, HB2, t, NT);
        for (int q = t; q < HB2; q += NT) {
            int incl = cnt[q];
            int excl = (q < HB2 - 1) ? cnt[q + 1] : 0;
            if (excl < k2 && k2 <= incl) {
                s_strad = q; s_krem = k2 - excl;
                s_above = (q < HB2 - 1) ? sm[q + 1] : 0.f;
            }
        }
        __syncthreads();
        int s2 = s_strad, krem = s_krem;
        total += s_above;
        // tail: approximate remaining krem elems by bucket floor (width ~ v*2^-15 — negligible vs threshold)
        float tval = __uint_as_float((((unsigned)s1) << 19) | (((unsigned)s2) << 8));
        total += (float)krem * tval;
    }

    // contribute + last-block finalize
    if (t == 0) {
        if (k > 0) atomicAdd(&acc[1], total);
        __threadfence();
        unsigned old = atomicAdd(done_ctr, 1u);
        s_last = (old == (unsigned)gridDim.x - 1u) ? 1 : 0;
    }
    __syncthreads();
    if (s_last) {
        __threadfence();
        float vn = 0.f, va = 0.f, vb = 0.f;
        for (int q = t; q < B; q += NT) {
            vn += (float)num_pos[q];
            va += accB[q * 2 + 0];
            vb += accB[q * 2 + 1];
        }
#pragma unroll
        for (int off = 32; off >= 1; off >>= 1) {
            vn += __shfl_down(vn, off, 64);
            va += __shfl_down(va, off, 64);
            vb += __shfl_down(vb, off, 64);
        }
        if ((t & 63) == 0) { wsum[t >> 6] = vn; wsA[t >> 6] = va; wsB[t >> 6] = vb; }
        __syncthreads();
        if (t == 0) {
            float n = 0.f, a = 0.f, bsum = 0.f;
#pragma unroll
            for (int w = 0; w < 8; w++) { n += wsum[w]; a += wsA[w]; bsum += wsB[w]; }
            float l2 = atomicAdd(&acc[1], 0.0f);
            out[0] = a / n;
            out[1] = (bsum + l2) / n;
        }
    }
}

extern "C" void kernel_launch(void* const* d_in, const int* in_sizes, int n_in,
                              void* d_out, int out_size, void* d_ws, size_t ws_size,
                              hipStream_t stream)
{
    const float* loc     = (const float*)d_in[0];
    const float* conf    = (const float*)d_in[1];
    const float* targets = (const float*)d_in[2];
    const float* priors  = (const float*)d_in[3];
    float* out = (float*)d_out;

    const int N = in_sizes[3] / 4;
    const int BN = in_sizes[0] / 4;
    const int B = BN / N;
    const int NOBJ = in_sizes[2] / (B * 5);
    const int SLICES = 8;
    const int CHUNK = (N + SLICES - 1) / SLICES;
    const int TPB = (N + 255) / 256;     // tiles per batch
    const int BPB = 6;                   // blocks per batch -> 768 blocks = 3/CU

    // workspace layout
    char* w = (char*)d_ws;
    float*    lc_ws   = (float*)w;                         size_t off = (size_t)BN * 4;
    float*    bpi_val = (float*)(w + off);                 off += (size_t)B * SLICES * 16 * 4;
    int*      bpi_idx = (int*)(w + off);                   off += (size_t)B * SLICES * 16 * 4;
    int*      num_pos = (int*)(w + off);                   off += (size_t)B * 4;
    float*    accB    = (float*)(w + off);                 off += (size_t)B * 2 * 4;
    float*    acc     = (float*)(w + off);                 off += 16;
    unsigned* done    = (unsigned*)(w + off);              off += 16;

    dim3 gA(SLICES, B);
    kA_best_prior<<<gA, 256, 0, stream>>>(targets, priors, bpi_val, bpi_idx,
                                          num_pos, accB, acc, done, N, NOBJ, SLICES, CHUNK, B);

    kB_main<<<B * BPB, 256, 0, stream>>>(loc, conf, targets, priors, bpi_val, bpi_idx,
                                         lc_ws, num_pos, accB, N, NOBJ, SLICES, TPB, BPB);

    kC_topk<<<B, 512, 0, stream>>>(lc_ws, num_pos, accB, acc, done, out, N, B);
}

// Round 7
// 225.854 us; speedup vs baseline: 1.9318x; 1.1564x over previous
//
#include <hip/hip_runtime.h>
#include <cstdint>
#include <cstddef>

#define HB1 4096         // kC level-1 buckets (u>>19)
#define HB2 2048         // kC level-2 buckets ((u>>8)&0x7FF)
#define CMAX 21
#define IOU_T 0.5f

__device__ __forceinline__ float sl1(float x) {
    float ax = fabsf(x);
    return ax < 1.0f ? 0.5f * x * x : ax - 0.5f;
}

// ---------------- Kernel A: per-truth argmax over prior slices (+ zero-init fold) ----------------
__global__ __launch_bounds__(256) void kA_best_prior(
    const float* __restrict__ targets, const float* __restrict__ priors,
    float* __restrict__ bpi_val, int* __restrict__ bpi_idx,
    int* __restrict__ num_pos_g, float* __restrict__ accB_g,
    float* __restrict__ acc_g, unsigned* __restrict__ done_g,
    int N, int NOBJ, int SLICES, int CHUNK, int B)
{
    const int s = blockIdx.x, b = blockIdx.y, t = threadIdx.x;
    __shared__ float tb[16 * 4];
    __shared__ float ta[16];
    __shared__ float wv[4 * 16];
    __shared__ int   wi[4 * 16];

    if (s == 0 && b == 0) {
        for (int q = t; q < B; q += 256) num_pos_g[q] = 0;
        for (int q = t; q < 2 * B; q += 256) accB_g[q] = 0.f;
        if (t < 4) acc_g[t] = 0.f;
        if (t == 0) *done_g = 0u;
    }

    if (t < 16) {
        if (t < NOBJ) {
            const float* tr = targets + ((size_t)b * NOBJ + t) * 5;
            float x0 = tr[0], y0 = tr[1], x1 = tr[2], y1 = tr[3];
            tb[t * 4 + 0] = x0; tb[t * 4 + 1] = y0;
            tb[t * 4 + 2] = x1; tb[t * 4 + 3] = y1;
            ta[t] = (x1 - x0) * (y1 - y0);
        } else {
            tb[t * 4 + 0] = 0.f; tb[t * 4 + 1] = 0.f;
            tb[t * 4 + 2] = 0.f; tb[t * 4 + 3] = 0.f;
            ta[t] = 0.f;
        }
    }
    __syncthreads();

    float bv[16]; int bi[16];
#pragma unroll
    for (int j = 0; j < 16; j++) { bv[j] = -1.0f; bi[j] = 0x7fffffff; }

    const int start = s * CHUNK;
    const int end = min(start + CHUNK, N);
    for (int i = start + t; i < end; i += 256) {
        float4 p = ((const float4*)priors)[i];
        float bx0 = p.x - p.z * 0.5f, by0 = p.y - p.w * 0.5f;
        float bx1 = p.x + p.z * 0.5f, by1 = p.y + p.w * 0.5f;
        float ab = (bx1 - bx0) * (by1 - by0);
#pragma unroll
        for (int j = 0; j < 16; j++) {
            float iw = fminf(tb[j * 4 + 2], bx1) - fmaxf(tb[j * 4 + 0], bx0);
            float ih = fminf(tb[j * 4 + 3], by1) - fmaxf(tb[j * 4 + 1], by0);
            iw = fmaxf(iw, 0.f); ih = fmaxf(ih, 0.f);
            float inter = iw * ih;
            float iou = inter / (ta[j] + ab - inter);
            if (iou > bv[j] || (iou == bv[j] && i < bi[j])) { bv[j] = iou; bi[j] = i; }
        }
    }

#pragma unroll
    for (int off = 32; off >= 1; off >>= 1) {
#pragma unroll
        for (int j = 0; j < 16; j++) {
            float v2 = __shfl_down(bv[j], off, 64);
            int   i2 = __shfl_down(bi[j], off, 64);
            if (v2 > bv[j] || (v2 == bv[j] && i2 < bi[j])) { bv[j] = v2; bi[j] = i2; }
        }
    }
    const int wid = t >> 6, lane = t & 63;
    if (lane == 0) {
#pragma unroll
        for (int j = 0; j < 16; j++) { wv[wid * 16 + j] = bv[j]; wi[wid * 16 + j] = bi[j]; }
    }
    __syncthreads();
    if (t < 16) {
        float v = wv[t]; int idx = wi[t];
#pragma unroll
        for (int w = 1; w < 4; w++) {
            float v2 = wv[w * 16 + t]; int i2 = wi[w * 16 + t];
            if (v2 > v || (v2 == v && i2 < idx)) { v = v2; idx = i2; }
        }
        if (t < NOBJ) {
            int o = (b * SLICES + s) * 16 + t;
            bpi_val[o] = v;
            bpi_idx[o] = idx;
        }
    }
}

// ---------------- Kernel B: software-pipelined multi-tile (reg-staged double-buffered LDS) ----------------
#define IOU_STEP(j) { \
    float4 tj = tb4[j]; \
    float taj = (tj.z - tj.x) * (tj.w - tj.y); \
    float iw = fminf(tj.z, bx1) - fmaxf(tj.x, bx0); \
    float ih = fminf(tj.w, by1) - fmaxf(tj.y, by0); \
    iw = fmaxf(iw, 0.f); ih = fmaxf(ih, 0.f); \
    float inter = iw * ih; \
    float iou = inter * __builtin_amdgcn_rcpf(taj + ab - inter); \
    if (iou > bto) { bto = iou; bti = (j); } }

__global__ __launch_bounds__(256, 3) void kB_main(
    const float* __restrict__ loc, const float* __restrict__ conf,
    const float* __restrict__ targets, const float* __restrict__ priors,
    const float* __restrict__ bpi_val, const int* __restrict__ bpi_idx,
    float* __restrict__ lc_out, int* __restrict__ num_pos, float* __restrict__ accB,
    int N, int NOBJ, int SLICES, int TPB, int BPB)
{
    const int g = blockIdx.x;
    const int b = g / BPB;
    const int j0 = g % BPB;
    const int t = threadIdx.x;
    const int wid = t >> 6, lane = t & 63;

    __shared__ __align__(16) float buf[2][256 * CMAX];   // 2 x 21504 B
    __shared__ __align__(16) float tb[16 * 4];
    __shared__ float tl[16];
    __shared__ __align__(16) int bpi_s[16];
    __shared__ float wred[4 * 3];

    if (t < 16) {
        if (t < NOBJ) {
            const float* tr = targets + ((size_t)b * NOBJ + t) * 5;
            tb[t * 4 + 0] = tr[0]; tb[t * 4 + 1] = tr[1];
            tb[t * 4 + 2] = tr[2]; tb[t * 4 + 3] = tr[3];
            tl[t] = tr[4];
            float bv = -1.f; int bi = 0x7fffffff;
            for (int s2 = 0; s2 < SLICES; s2++) {
                int o = (b * SLICES + s2) * 16 + t;
                float v = bpi_val[o]; int idx = bpi_idx[o];
                if (v > bv || (v == bv && idx < bi)) { bv = v; bi = idx; }
            }
            bpi_s[t] = bi;
        } else {
            tb[t * 4 + 0] = 0.f; tb[t * 4 + 1] = 0.f; tb[t * 4 + 2] = 0.f; tb[t * 4 + 3] = 0.f;
            tl[t] = 0.f; bpi_s[t] = -1;
        }
    }

    const float* confB = conf + (size_t)b * N * CMAX;
    const float* locB  = loc + (size_t)b * N * 4;

    float4 r0, r1, r2, r3, r4, r5, pld, ppr;

    auto stage = [&](int xx) {
        int i0s = xx * 256;
        int rows_s = min(256, N - i0s);
        int nf4s = (rows_s * CMAX) >> 2;
        const float4* s4 = (const float4*)(confB + (size_t)i0s * CMAX);
        if (t + 0    < nf4s) r0 = s4[t + 0];
        if (t + 256  < nf4s) r1 = s4[t + 256];
        if (t + 512  < nf4s) r2 = s4[t + 512];
        if (t + 768  < nf4s) r3 = s4[t + 768];
        if (t + 1024 < nf4s) r4 = s4[t + 1024];
        if (t + 1280 < nf4s) r5 = s4[t + 1280];
        if (t < rows_s) {
            ppr = ((const float4*)priors)[i0s + t];
            pld = ((const float4*)locB)[i0s + t];
        }
    };

    float ll = 0.f, plc = 0.f, np = 0.f;
    int x = j0, p = 0;
    if (x < TPB) stage(x);

    while (x < TPB) {
        const int i0 = x * 256;
        const int rows = min(256, N - i0);
        const int nf4 = (rows * CMAX) >> 2;

        float4 myp = ppr, myl = pld;

        float4* bp4f = (float4*)buf[p];
        if (t + 0    < nf4) bp4f[t + 0]    = r0;
        if (t + 256  < nf4) bp4f[t + 256]  = r1;
        if (t + 512  < nf4) bp4f[t + 512]  = r2;
        if (t + 768  < nf4) bp4f[t + 768]  = r3;
        if (t + 1024 < nf4) bp4f[t + 1024] = r4;
        if (t + 1280 < nf4) bp4f[t + 1280] = r5;
        __syncthreads();

        int xn = x + BPB;
        if (xn < TPB) stage(xn);

        if (t < rows) {
            const int i = i0 + t;
            float4 pp = myp;
            float bx0 = pp.x - pp.z * 0.5f, by0 = pp.y - pp.w * 0.5f;
            float bx1 = pp.x + pp.z * 0.5f, by1 = pp.y + pp.w * 0.5f;
            float ab = (bx1 - bx0) * (by1 - by0);
            float bto = -1.f; int bti = 0;
            const float4* tb4 = (const float4*)tb;
            if (NOBJ == 16) {
#pragma unroll
                for (int j = 0; j < 16; j++) IOU_STEP(j);
            } else {
                for (int j = 0; j < NOBJ; j++) IOU_STEP(j);
            }
            const int4* bp4 = (const int4*)bpi_s;
#pragma unroll
            for (int jj = 0; jj < 4; jj++) {
                int4 q = bp4[jj];
                if (q.x == i) { bto = 2.0f; bti = jj * 4 + 0; }
                if (q.y == i) { bto = 2.0f; bti = jj * 4 + 1; }
                if (q.z == i) { bto = 2.0f; bti = jj * 4 + 2; }
                if (q.w == i) { bto = 2.0f; bti = jj * 4 + 3; }
            }
            bool pos = !(bto < IOU_T);
            if (pos) {
                float4 tj = tb4[bti];
                float rz = __builtin_amdgcn_rcpf(pp.z);
                float rw = __builtin_amdgcn_rcpf(pp.w);
                float gcx = ((tj.x + tj.z) * 0.5f - pp.x) * (10.0f * rz);
                float gcy = ((tj.y + tj.w) * 0.5f - pp.y) * (10.0f * rw);
                float gw = __logf((tj.z - tj.x) * rz) * 5.0f;
                float gh = __logf((tj.w - tj.y) * rw) * 5.0f;
                ll += sl1(myl.x - gcx) + sl1(myl.y - gcy) + sl1(myl.z - gw) + sl1(myl.w - gh);
                np += 1.f;
            }
            int cf = pos ? ((int)tl[bti] + 1) : 0;
            const float* cr = buf[p] + t * CMAX;
            float m = cr[0];
#pragma unroll
            for (int c = 1; c < CMAX; c++) m = fmaxf(m, cr[c]);
            float ssum = 0.f;
#pragma unroll
            for (int c = 0; c < CMAX; c++) ssum += __expf(cr[c] - m);
            float lse = m + __logf(ssum);
            float lossc = lse - cr[cf];
            if (pos) plc += lossc;
            float lcv = pos ? 0.f : lossc;
            lcv = fmaxf(lcv, 0.f);
            lc_out[(size_t)b * N + i] = lcv;
        }
        p ^= 1;
        x = xn;
    }

#pragma unroll
    for (int off = 32; off >= 1; off >>= 1) {
        ll  += __shfl_down(ll, off, 64);
        plc += __shfl_down(plc, off, 64);
        np  += __shfl_down(np, off, 64);
    }
    if (lane == 0) { wred[wid * 3 + 0] = ll; wred[wid * 3 + 1] = plc; wred[wid * 3 + 2] = np; }
    __syncthreads();
    if (t == 0) {
        float a0 = 0.f, a1 = 0.f, a2 = 0.f;
#pragma unroll
        for (int w = 0; w < 4; w++) { a0 += wred[w * 3 + 0]; a1 += wred[w * 3 + 1]; a2 += wred[w * 3 + 2]; }
        atomicAdd(&accB[b * 2 + 0], a0);
        atomicAdd(&accB[b * 2 + 1], a1);
        atomicAdd(&num_pos[b], (int)a2);
    }
}

// ---------------- Kernel C: 2-level radix select, hierarchical shuffle suffix-scan ----------------
// wave-inclusive suffix scan (lane i gets sum over lanes [i,63])
__device__ __forceinline__ void wave_sufscan(int& c, float& s, int lane) {
#pragma unroll
    for (int off = 1; off < 64; off <<= 1) {
        int c2 = __shfl_down(c, off, 64);
        float s2 = __shfl_down(s, off, 64);
        if (lane + off < 64) { c += c2; s += s2; }
    }
}

__global__ __launch_bounds__(1024) void kC_topk(
    const float* __restrict__ lc, const int* __restrict__ num_pos,
    const float* __restrict__ accB,
    float* __restrict__ acc, unsigned* __restrict__ done_ctr,
    float* __restrict__ out, int N, int B)
{
    const int b = blockIdx.x, t = threadIdx.x;
    const int NT = 1024;
    const int wid = t >> 6, lane = t & 63;   // 16 waves
    __shared__ __align__(16) int   cnt[HB1];
    __shared__ __align__(16) float sm[HB1];
    __shared__ int   wc[16];
    __shared__ float ws[16];
    __shared__ int s_strad, s_krem;
    __shared__ float s_above;
    __shared__ int s_last;
    __shared__ float wsum[16], wsA[16], wsB[16];

    const int k = min(3 * num_pos[b], N - 1);
    const float* lcb = lc + (size_t)b * N;
    float total = 0.f;

    if (k > 0) {
        // ---- Level 1: bits [30:19] (4096 buckets), thread owns 4 ----
        ((int4*)cnt)[t] = make_int4(0, 0, 0, 0);
        ((float4*)sm)[t] = make_float4(0.f, 0.f, 0.f, 0.f);
        __syncthreads();
        const int n4 = N >> 2;
        const float4* lcb4 = (const float4*)lcb;
        for (int i = t; i < n4; i += NT) {
            float4 v = lcb4[i];
            { unsigned u = __float_as_uint(v.x) >> 19; atomicAdd(&cnt[u], 1); atomicAdd(&sm[u], v.x); }
            { unsigned u = __float_as_uint(v.y) >> 19; atomicAdd(&cnt[u], 1); atomicAdd(&sm[u], v.y); }
            { unsigned u = __float_as_uint(v.z) >> 19; atomicAdd(&cnt[u], 1); atomicAdd(&sm[u], v.z); }
            { unsigned u = __float_as_uint(v.w) >> 19; atomicAdd(&cnt[u], 1); atomicAdd(&sm[u], v.w); }
        }
        for (int i = (n4 << 2) + t; i < N; i += NT) {
            float v = lcb[i];
            unsigned u = __float_as_uint(v) >> 19;
            atomicAdd(&cnt[u], 1); atomicAdd(&sm[u], v);
        }
        __syncthreads();
        {
            int4  cv = ((const int4*)cnt)[t];
            float4 sv = ((const float4*)sm)[t];
            int   ci = cv.x + cv.y + cv.z + cv.w;
            float si = sv.x + sv.y + sv.z + sv.w;
            wave_sufscan(ci, si, lane);
            if (lane == 0) { wc[wid] = ci; ws[wid] = si; }
            __syncthreads();
            int cab = 0; float sab = 0.f;
            for (int w = wid + 1; w < 16; w++) { cab += wc[w]; sab += ws[w]; }
            int   i0c = ci + cab;          float f0 = si + sab;     // incl(4t)
            int   i1c = i0c - cv.x;        float f1 = f0 - sv.x;    // incl(4t+1) = excl(4t)
            int   i2c = i1c - cv.y;        float f2 = f1 - sv.y;
            int   i3c = i2c - cv.z;        float f3 = f2 - sv.z;
            int   i4c = i3c - cv.w;        // excl(4t+3)
            if (i1c < k && k <= i0c) { s_strad = 4 * t + 0; s_krem = k - i1c; s_above = f1; }
            if (i2c < k && k <= i1c) { s_strad = 4 * t + 1; s_krem = k - i2c; s_above = f2; }
            if (i3c < k && k <= i2c) { s_strad = 4 * t + 2; s_krem = k - i3c; s_above = f3; }
            if (i4c < k && k <= i3c) { s_strad = 4 * t + 3; s_krem = k - i4c; s_above = f3 - sv.w; }
        }
        __syncthreads();
        const int s1 = s_strad, k2 = s_krem;
        total += s_above;

        // ---- Level 2: bits [18:8] (2048 buckets) within L1 bucket s1, thread owns 2 ----
        __syncthreads();   // ensure all threads read s_strad/s_above before reuse
        ((int2*)cnt)[t] = make_int2(0, 0);
        ((float2*)sm)[t] = make_float2(0.f, 0.f);
        __syncthreads();
        for (int i = t; i < N; i += NT) {
            float v = lcb[i];
            unsigned u = __float_as_uint(v);
            if ((int)(u >> 19) == s1) {
                int q = (int)((u >> 8) & 0x7FF);
                atomicAdd(&cnt[q], 1); atomicAdd(&sm[q], v);
            }
        }
        __syncthreads();
        {
            int2  cv = ((const int2*)cnt)[t];
            float2 sv = ((const float2*)sm)[t];
            int   ci = cv.x + cv.y;
            float si = sv.x + sv.y;
            wave_sufscan(ci, si, lane);
            if (lane == 0) { wc[wid] = ci; ws[wid] = si; }
            __syncthreads();
            int cab = 0; float sab = 0.f;
            for (int w = wid + 1; w < 16; w++) { cab += wc[w]; sab += ws[w]; }
            int   i0c = ci + cab;       float f0 = si + sab;    // incl(2t)
            int   i1c = i0c - cv.x;     float f1 = f0 - sv.x;   // incl(2t+1) = excl(2t)
            int   i2c = i1c - cv.y;     // excl(2t+1)
            if (i1c < k2 && k2 <= i0c) { s_strad = 2 * t + 0; s_krem = k2 - i1c; s_above = f1; }
            if (i2c < k2 && k2 <= i1c) { s_strad = 2 * t + 1; s_krem = k2 - i2c; s_above = f1 - sv.y; }
        }
        __syncthreads();
        const int s2 = s_strad, krem = s_krem;
        total += s_above;
        // tail: remaining krem elems at bucket floor (relative width 2^-15 — negligible vs threshold)
        float tval = __uint_as_float((((unsigned)s1) << 19) | (((unsigned)s2) << 8));
        total += (float)krem * tval;
    }

    // contribute + last-block finalize
    if (t == 0) {
        if (k > 0) atomicAdd(&acc[1], total);
        __threadfence();
        unsigned old = atomicAdd(done_ctr, 1u);
        s_last = (old == (unsigned)gridDim.x - 1u) ? 1 : 0;
    }
    __syncthreads();
    if (s_last) {
        __threadfence();
        float vn = 0.f, va = 0.f, vb = 0.f;
        for (int q = t; q < B; q += NT) {
            vn += (float)num_pos[q];
            va += accB[q * 2 + 0];
            vb += accB[q * 2 + 1];
        }
#pragma unroll
        for (int off = 32; off >= 1; off >>= 1) {
            vn += __shfl_down(vn, off, 64);
            va += __shfl_down(va, off, 64);
            vb += __shfl_down(vb, off, 64);
        }
        if (lane == 0) { wsum[wid] = vn; wsA[wid] = va; wsB[wid] = vb; }
        __syncthreads();
        if (t == 0) {
            float n = 0.f, a = 0.f, bsum = 0.f;
#pragma unroll
            for (int w = 0; w < 16; w++) { n += wsum[w]; a += wsA[w]; bsum += wsB[w]; }
            float l2 = atomicAdd(&acc[1], 0.0f);
            out[0] = a / n;
            out[1] = (bsum + l2) / n;
        }
    }
}

extern "C" void kernel_launch(void* const* d_in, const int* in_sizes, int n_in,
                              void* d_out, int out_size, void* d_ws, size_t ws_size,
                              hipStream_t stream)
{
    const float* loc     = (const float*)d_in[0];
    const float* conf    = (const float*)d_in[1];
    const float* targets = (const float*)d_in[2];
    const float* priors  = (const float*)d_in[3];
    float* out = (float*)d_out;

    const int N = in_sizes[3] / 4;
    const int BN = in_sizes[0] / 4;
    const int B = BN / N;
    const int NOBJ = in_sizes[2] / (B * 5);
    const int SLICES = 8;
    const int CHUNK = (N + SLICES - 1) / SLICES;
    const int TPB = (N + 255) / 256;     // tiles per batch
    const int BPB = 6;                   // blocks per batch -> 768 blocks = 3/CU

    // workspace layout
    char* w = (char*)d_ws;
    float*    lc_ws   = (float*)w;                         size_t off = (size_t)BN * 4;
    float*    bpi_val = (float*)(w + off);                 off += (size_t)B * SLICES * 16 * 4;
    int*      bpi_idx = (int*)(w + off);                   off += (size_t)B * SLICES * 16 * 4;
    int*      num_pos = (int*)(w + off);                   off += (size_t)B * 4;
    float*    accB    = (float*)(w + off);                 off += (size_t)B * 2 * 4;
    float*    acc     = (float*)(w + off);                 off += 16;
    unsigned* done    = (unsigned*)(w + off);              off += 16;

    dim3 gA(SLICES, B);
    kA_best_prior<<<gA, 256, 0, stream>>>(targets, priors, bpi_val, bpi_idx,
                                          num_pos, accB, acc, done, N, NOBJ, SLICES, CHUNK, B);

    kB_main<<<B * BPB, 256, 0, stream>>>(loc, conf, targets, priors, bpi_val, bpi_idx,
                                         lc_ws, num_pos, accB, N, NOBJ, SLICES, TPB, BPB);

    kC_topk<<<B, 1024, 0, stream>>>(lc_ws, num_pos, accB, acc, done, out, N, B);
}